// Round 11
// baseline (665.044 us; speedup 1.0000x reference)
//
#include <hip/hip_runtime.h>
#include <math.h>

#define N_NODES 6000
#define N_EDGES 192000
#define H 128
#define NHEADS 4
#define HCAT 640
#define NPAD 6016       // K/partial arrays padded to 6016 rows
#define NTILES 188      // ceil(6000/32)
#define LOG2E 1.4426950408889634f

typedef unsigned short ushort_t;
typedef __attribute__((ext_vector_type(8))) short short8;
typedef __attribute__((ext_vector_type(16))) float f32x16;

__device__ __forceinline__ void bf16split(float x, ushort_t& hi, ushort_t& lo) {
    unsigned ub = __float_as_uint(x);
    unsigned hb = ub & 0xffff0000u;
    float l = x - __uint_as_float(hb);
    hi = (ushort_t)(hb >> 16);
    lo = (ushort_t)(__float_as_uint(l) >> 16);
}

__device__ __forceinline__ void gll16(const ushort_t* g, ushort_t* l) {
    __builtin_amdgcn_global_load_lds((const __attribute__((address_space(1))) void*)g,
                                     (__attribute__((address_space(3))) void*)l, 16, 0, 0);
}

// ---------------- CSR build (both graphs per launch) ----------------
__global__ void zero_ints(int* p, int n) {
    int i = blockIdx.x * 256 + threadIdx.x;
    if (i < n) p[i] = 0;
}

__global__ void hist2(const int* __restrict__ eA, const int* __restrict__ eB,
                      int* __restrict__ cnt) {
    int e = blockIdx.x * 256 + threadIdx.x;
    int z = blockIdx.y;
    const int* edges = z ? eB : eA;
    if (e < N_EDGES) atomicAdd(&cnt[z * N_NODES + edges[N_EDGES + e]], 1);
}

// grid 2, 1024 threads: exclusive prefix over 6000 counts + dinv
__global__ __launch_bounds__(1024)
void scan2(const int* __restrict__ cnt_all, int* __restrict__ rs_all,
           float* __restrict__ dinv_all) {
    __shared__ int ps[1024];
    int z = blockIdx.x;
    const int* cnt = cnt_all + z * N_NODES;
    int* row_start = rs_all + z * (N_NODES + 1);
    float* dinv = dinv_all + z * N_NODES;
    int t = threadIdx.x;
    int base = t * 6;
    int local[6];
    int s = 0;
#pragma unroll
    for (int j = 0; j < 6; ++j) {
        int idx = base + j;
        int v = (idx < N_NODES) ? cnt[idx] : 0;
        local[j] = s;
        s += v;
        if (idx < N_NODES) dinv[idx] = rsqrtf((float)(v + 1));
    }
    ps[t] = s;
    __syncthreads();
    for (int off = 1; off < 1024; off <<= 1) {
        int v = (t >= off) ? ps[t - off] : 0;
        __syncthreads();
        ps[t] += v;
        __syncthreads();
    }
    int ex = (t > 0) ? ps[t - 1] : 0;
#pragma unroll
    for (int j = 0; j < 6; ++j) {
        int idx = base + j;
        if (idx < N_NODES) row_start[idx] = ex + local[j];
    }
    if (t == 1023) row_start[N_NODES] = ps[1023];
}

__global__ void place2(const int* __restrict__ eA, const int* __restrict__ eB,
                       const int* __restrict__ rs_all, int* __restrict__ cur_all,
                       int* __restrict__ eslot_all) {
    int e = blockIdx.x * 256 + threadIdx.x;
    int z = blockIdx.y;
    const int* edges = z ? eB : eA;
    if (e < N_EDGES) {
        int tg = edges[N_EDGES + e];
        int p = atomicAdd(&cur_all[z * N_NODES + tg], 1);
        eslot_all[(size_t)z * N_EDGES + rs_all[z * (N_NODES + 1) + tg] + p] = e;
    }
}

// ---------------- layer-1 reorder: aggregate raw 3-dim x first ----------------
__global__ __launch_bounds__(256)
void gather_x3(const float* __restrict__ xA, const float* __restrict__ xB,
               const int* __restrict__ eA, const int* __restrict__ eB,
               const int* __restrict__ eslot_all, const int* __restrict__ rs_all,
               const float* __restrict__ dinv_all,
               float* __restrict__ outA, float* __restrict__ outB) {
    int z = blockIdx.y;
    int n = blockIdx.x * 256 + threadIdx.x;
    if (n >= N_NODES) return;
    const int* edges = z ? eB : eA;
    const int* eslot = eslot_all + (size_t)z * N_EDGES;
    const int* row_start = rs_all + z * (N_NODES + 1);
    const float* x = z ? xB : xA;
    const float* dv = dinv_all + z * N_NODES;
    float* out = z ? outB : outA;
    float di = dv[n];
    float a0 = x[n * 3 + 0] * di * di;
    float a1 = x[n * 3 + 1] * di * di;
    float a2 = x[n * 3 + 2] * di * di;
    int s0 = row_start[n], s1 = row_start[n + 1];
    for (int i = s0; i < s1; ++i) {
        int e = eslot[i];
        int s = edges[e];
        float nr = dv[s] * di;
        a0 += x[s * 3 + 0] * nr;
        a1 += x[s * 3 + 1] * nr;
        a2 += x[s * 3 + 2] * nr;
    }
    out[n * 3 + 0] = a0; out[n * 3 + 1] = a1; out[n * 3 + 2] = a2;
}

// ---------------- GCN pieces (both graphs per launch) ----------------
__global__ __launch_bounds__(256)
void gcn_gemm2(const float* __restrict__ hinA, const float* __restrict__ hinB,
               const float* __restrict__ WA, const float* __restrict__ WB,
               float* __restrict__ hwA, float* __restrict__ hwB, int in_dim,
               const float* __restrict__ bA, const float* __restrict__ bB, int do_relu) {
    __shared__ float xs[16 * H];
    int z = blockIdx.y;
    const float* hin = z ? hinB : hinA;
    const float* W = z ? WB : WA;
    float* hw = z ? hwB : hwA;
    const float* b = z ? bB : bA;
    int n0 = blockIdx.x * 16;
    int t = threadIdx.x;
    int f = t & (H - 1);
    int g = t >> 7;
    for (int i = t; i < 16 * H; i += 256) {
        int r = i >> 7, c = i & (H - 1);
        xs[i] = (c < in_dim) ? hin[(size_t)(n0 + r) * in_dim + c] : 0.f;
    }
    __syncthreads();
    float acc[8];
#pragma unroll
    for (int j = 0; j < 8; ++j) acc[j] = 0.f;
    for (int d = 0; d < in_dim; ++d) {
        float w = W[d * H + f];
#pragma unroll
        for (int j = 0; j < 8; ++j) acc[j] += xs[(g * 8 + j) * H + d] * w;
    }
    if (do_relu) {
        float bias = b[f];
#pragma unroll
        for (int j = 0; j < 8; ++j)
            hw[(size_t)(n0 + g * 8 + j) * H + f] = fmaxf(acc[j] + bias, 0.f);
    } else {
#pragma unroll
        for (int j = 0; j < 8; ++j) hw[(size_t)(n0 + g * 8 + j) * H + f] = acc[j];
    }
}

__global__ __launch_bounds__(H)
void gather2(const int* __restrict__ eA, const int* __restrict__ eB,
             const int* __restrict__ eslot_all, const int* __restrict__ rs_all,
             const float* __restrict__ hwA, const float* __restrict__ hwB,
             const float* __restrict__ dinv_all,
             const float* __restrict__ bA, const float* __restrict__ bB,
             float* __restrict__ outA, float* __restrict__ outB) {
    __shared__ int ssrc[128];
    __shared__ float snrm[128];
    int z = blockIdx.y;
    const int* edges = z ? eB : eA;
    const int* eslot = eslot_all + (size_t)z * N_EDGES;
    const int* row_start = rs_all + z * (N_NODES + 1);
    const float* hw = z ? hwB : hwA;
    const float* dinv = dinv_all + z * N_NODES;
    const float* b = z ? bB : bA;
    float* out = z ? outB : outA;

    int tg = blockIdx.x, f = threadIdx.x;
    int s0 = row_start[tg], s1 = row_start[tg + 1];
    float di = dinv[tg];
    float acc = hw[(size_t)tg * H + f] * di * di;
    for (int base = s0; base < s1; base += 128) {
        int cnt = min(128, s1 - base);
        __syncthreads();
        if (f < cnt) {
            int e = eslot[base + f];
            int s = edges[e];
            ssrc[f] = s;
            snrm[f] = dinv[s] * di;
        }
        __syncthreads();
        for (int i = 0; i < cnt; ++i)
            acc += hw[(size_t)ssrc[i] * H + f] * snrm[i];
    }
    float v = acc + b[f];
    out[(size_t)tg * H + f] = v > 0.f ? v : 0.f;
}

// ---------------- merged q/k projection (Q scaled by log2e) ----------------
__global__ __launch_bounds__(256)
void qk_kernel2(const float* __restrict__ qs, const float* __restrict__ xg,
                const float* __restrict__ Wa, const float* __restrict__ ba,
                ushort_t* __restrict__ Qh, ushort_t* __restrict__ Ql,
                ushort_t* __restrict__ Khs, ushort_t* __restrict__ Kls) {
    __shared__ float xs[2][16][H];
    int n0 = blockIdx.x * 16, head = blockIdx.y;
    int t = threadIdx.x;
    int f = t & (H - 1);
    int g = t >> 7;
    for (int i = t; i < 2 * 16 * H; i += 256) {
        int which = i >> 11;
        int rem = i & 2047;
        int row = rem >> 7, col = rem & 127;
        xs[which][row][col] = which ? xg[(size_t)(n0 + row) * H + col]
                                    : qs[(size_t)(n0 + row) * H + col];
    }
    __syncthreads();
    const float* W = Wa + (size_t)head * H * H;
    float bias = ba[head * H + f];
    float acc[16];
#pragma unroll
    for (int j = 0; j < 16; ++j) acc[j] = bias;
    for (int d = 0; d < H; ++d) {
        float w = W[d * H + f];
#pragma unroll
        for (int j = 0; j < 16; ++j) acc[j] += xs[g][j][d] * w;
    }
#pragma unroll
    for (int j = 0; j < 16; ++j) {
        int n = n0 + j;
        ushort_t hi, lo;
        if (g == 0) {
            bf16split(acc[j] * LOG2E, hi, lo);   // fold log2e: softmax in exp2 domain
            size_t idx = ((size_t)(head * N_NODES + n) << 7) + f;
            Qh[idx] = hi; Ql[idx] = lo;
        } else {
            bf16split(acc[j], hi, lo);
            int pos = (((f >> 3) ^ (n & 15)) << 3) + (f & 7);
            size_t idx = ((size_t)(head * NPAD + n) << 7) + pos;
            Khs[idx] = hi; Kls[idx] = lo;
        }
    }
}

__global__ void zero_pad_k(ushort_t* __restrict__ Khs, ushort_t* __restrict__ Kls) {
    int i = blockIdx.x * 256 + threadIdx.x;
    if (i < NHEADS * 16 * H) {
        int head = i / (16 * H);
        int rest = i - head * 16 * H;
        int n = N_NODES + (rest >> 7);
        int f = rest & 127;
        size_t idx = ((size_t)(head * NPAD + n) << 7) + f;
        Khs[idx] = 0; Kls[idx] = 0;
    }
}

// ---------------- V transpose -> tiled swizzled bf16 hi/lo ----------------
__global__ __launch_bounds__(128)
void cvt_vt(const float* __restrict__ xg, ushort_t* __restrict__ Vth, ushort_t* __restrict__ Vtl) {
    __shared__ float vs[32][129];
    int t0 = blockIdx.x;
    int t = threadIdx.x;
    for (int c = t; c < 32 * 32; c += 128) {
        int row = c >> 5, col4 = (c & 31) << 2;
        int n = t0 * 32 + row;
        float4 v = (n < N_NODES) ? *(const float4*)&xg[(size_t)n * H + col4]
                                 : float4{0.f, 0.f, 0.f, 0.f};
        vs[row][col4 + 0] = v.x; vs[row][col4 + 1] = v.y;
        vs[row][col4 + 2] = v.z; vs[row][col4 + 3] = v.w;
    }
    __syncthreads();
    int d = t;
    size_t base = ((size_t)t0 * H + d) * 32;
#pragma unroll
    for (int oc = 0; oc < 4; ++oc) {
        int cc = oc ^ (d & 3);
        unsigned uh[4], ul[4];
#pragma unroll
        for (int j = 0; j < 4; ++j) {
            ushort_t h0, l0, h1, l1;
            bf16split(vs[cc * 8 + 2 * j][d], h0, l0);
            bf16split(vs[cc * 8 + 2 * j + 1][d], h1, l1);
            uh[j] = (unsigned)h0 | ((unsigned)h1 << 16);
            ul[j] = (unsigned)l0 | ((unsigned)l1 << 16);
        }
        *(uint4*)&Vth[base + oc * 8] = make_uint4(uh[0], uh[1], uh[2], uh[3]);
        *(uint4*)&Vtl[base + oc * 8] = make_uint4(ul[0], ul[1], ul[2], ul[3]);
    }
}

// ---------------- MFMA flash attention: deferred-PV + per-block phase stagger ----------------
// grid (47, NHEADS, NS), block 256 = 4 waves. Identical-period co-resident blocks
// phase-lock (MFMA phases align -> 41% MfmaUtil ceiling seen R5-R10); a pseudo-random
// 0..5k-cycle startup sleep anti-phases them so one block's softmax VALU overlaps the
// other's MFMA. Softmax in exp2 domain (Q pre-scaled by log2e).
__global__ __launch_bounds__(256, 2)
void attn_mfma8(const ushort_t* __restrict__ Qh, const ushort_t* __restrict__ Ql,
                const ushort_t* __restrict__ Khs, const ushort_t* __restrict__ Kls,
                const ushort_t* __restrict__ Vth, const ushort_t* __restrict__ Vtl,
                float* __restrict__ Opart, float* __restrict__ mlpart, int tps) {
    __shared__ ushort_t lds[2][4][4096];   // [buf][Kh,Kl,Vh,Vl] 64 KB
    const int head = blockIdx.y;
    const int sp = blockIdx.z;
    const int t = threadIdx.x;
    const int lane = t & 63;
    const int r = lane & 31;
    const int h = lane >> 5;
    const int w = t >> 6;
    const int q0w = blockIdx.x * 128 + w * 32;

    int t_begin = sp * tps;
    int t_end = t_begin + tps; if (t_end > NTILES) t_end = NTILES;

    const size_t kbase = (size_t)head * NPAD * H;
    const int o1 = t * 8, o2 = t * 8 + 2048;

    // Q B-fragments in registers
    int qr = q0w + r; if (qr > N_NODES - 1) qr = N_NODES - 1;
    const size_t qbase = ((size_t)(head * N_NODES + qr)) << 7;
    short8 qfh[8], qfl[8];
#pragma unroll
    for (int s = 0; s < 8; ++s) {
        qfh[s] = *(const short8*)&Qh[qbase + 16 * s + 8 * h];
        qfl[s] = *(const short8*)&Ql[qbase + 16 * s + 8 * h];
    }

    f32x16 O[4];
#pragma unroll
    for (int sub = 0; sub < 4; ++sub)
#pragma unroll
        for (int i = 0; i < 16; ++i) O[sub][i] = 0.f;
    float mrun = -1e30f, lrun = 0.f;
    short8 aPh[2], aPl[2];
    float alpha_prev = 1.f;
    int resc_prev = 0;

    // prologue: stage K(t_begin) into buf 0
    {
        const ushort_t* sKh = Khs + kbase + (size_t)t_begin * 4096;
        const ushort_t* sKl = Kls + kbase + (size_t)t_begin * 4096;
        gll16(sKh + o1, &lds[0][0][o1]); gll16(sKh + o2, &lds[0][0][o2]);
        gll16(sKl + o1, &lds[0][1][o1]); gll16(sKl + o2, &lds[0][1][o2]);
    }

    // ---- phase stagger: pseudo-random 0..~5400-cycle sleep, uniform per block ----
    {
        unsigned lin = blockIdx.x + 47u * (blockIdx.y + (unsigned)NHEADS * blockIdx.z);
        unsigned ph = (lin * 2654435761u) >> 29;   // 0..7
        for (unsigned i = 0; i < ph; ++i) __builtin_amdgcn_s_sleep(12);  // ~768 cyc each
    }

    for (int it = t_begin; it < t_end; ++it) {
        const int b = (it - t_begin) & 1;
        __syncthreads();   // buf[b] = K(it), V(it-1) staged; prior buf[b^1] reads done
        {   // prefetch K(it+1) and V(it) into buf[b^1]
            int nt = it + 1; if (nt >= t_end) nt = t_begin;
            const ushort_t* sKh = Khs + kbase + (size_t)nt * 4096;
            const ushort_t* sKl = Kls + kbase + (size_t)nt * 4096;
            const ushort_t* sVh = Vth + (size_t)it * 4096;
            const ushort_t* sVl = Vtl + (size_t)it * 4096;
            gll16(sKh + o1, &lds[b ^ 1][0][o1]); gll16(sKh + o2, &lds[b ^ 1][0][o2]);
            gll16(sKl + o1, &lds[b ^ 1][1][o1]); gll16(sKl + o2, &lds[b ^ 1][1][o2]);
            gll16(sVh + o1, &lds[b ^ 1][2][o1]); gll16(sVh + o2, &lds[b ^ 1][2][o2]);
            gll16(sVl + o1, &lds[b ^ 1][3][o1]); gll16(sVl + o2, &lds[b ^ 1][3][o2]);
        }
        const ushort_t* lKh = &lds[b][0][0];
        const ushort_t* lKl = &lds[b][1][0];
        const ushort_t* lVh = &lds[b][2][0];   // V(it-1)
        const ushort_t* lVl = &lds[b][3][0];

        // ---- S^T(it) = (Kh+Kl)(Qh+Ql)^T, dropping lo*lo ----
        f32x16 acc;
#pragma unroll
        for (int i = 0; i < 16; ++i) acc[i] = 0.f;
        const int krow = r * H;
#pragma unroll
        for (int s = 0; s < 8; ++s) {
            int cc = ((2 * s + h) ^ (r & 15)) << 3;
            short8 ah = *(const short8*)&lKh[krow + cc];
            short8 al = *(const short8*)&lKl[krow + cc];
            acc = __builtin_amdgcn_mfma_f32_32x32x16_bf16(ah, qfh[s], acc, 0, 0, 0);
            acc = __builtin_amdgcn_mfma_f32_32x32x16_bf16(ah, qfl[s], acc, 0, 0, 0);
            acc = __builtin_amdgcn_mfma_f32_32x32x16_bf16(al, qfh[s], acc, 0, 0, 0);
        }

        // ---- deferred PV(it-1): independent of acc ----
        if (it != t_begin) {
            if (resc_prev) {
#pragma unroll
                for (int i = 0; i < 16; ++i) {
                    int rowq = (i & 3) + 8 * (i >> 2) + 4 * h;
                    float a = __shfl(alpha_prev, rowq);
#pragma unroll
                    for (int sub = 0; sub < 4; ++sub) O[sub][i] *= a;
                }
            }
#pragma unroll
            for (int sub = 0; sub < 4; ++sub) {
                const int vrow = (32 * sub + r) * 32;
#pragma unroll
                for (int s2 = 0; s2 < 2; ++s2) {
                    int cc = (((2 * s2 + h) ^ (r & 3)) << 3);
                    short8 bh = *(const short8*)&lVh[vrow + cc];
                    short8 bl = *(const short8*)&lVl[vrow + cc];
                    O[sub] = __builtin_amdgcn_mfma_f32_32x32x16_bf16(aPh[s2], bh, O[sub], 0, 0, 0);
                    O[sub] = __builtin_amdgcn_mfma_f32_32x32x16_bf16(aPh[s2], bl, O[sub], 0, 0, 0);
                    O[sub] = __builtin_amdgcn_mfma_f32_32x32x16_bf16(aPl[s2], bh, O[sub], 0, 0, 0);
                }
            }
        }

        // ---- online softmax(it), exp2 domain ----
        float sv[16];
#pragma unroll
        for (int i = 0; i < 16; ++i) sv[i] = acc[i];
        int klim = N_NODES - (it << 5);
        if (klim < 32) {
#pragma unroll
            for (int i = 0; i < 16; ++i) {
                int row = (i & 3) + 8 * (i >> 2) + 4 * h;
                if (row >= klim) sv[i] = -1e30f;
            }
        }
        float tmax = sv[0];
#pragma unroll
        for (int i = 1; i < 16; ++i) tmax = fmaxf(tmax, sv[i]);
        tmax = fmaxf(tmax, __shfl_xor(tmax, 32));
        float mnew = fmaxf(mrun, tmax);
        float p[16];
        float psum = 0.f;
#pragma unroll
        for (int i = 0; i < 16; ++i) { p[i] = exp2f(sv[i] - mnew); psum += p[i]; }

        if (__ballot(mnew > mrun)) {
            float alpha = exp2f(mrun - mnew);
            lrun *= alpha;
            alpha_prev = alpha;
            resc_prev = 1;
        } else {
            resc_prev = 0;
        }
        lrun += psum;
        mrun = mnew;

        // ---- P(it) repack -> A-operand frags for next iter ----
        float pr[16];
#pragma unroll
        for (int i = 0; i < 16; ++i) pr[i] = __shfl_xor(p[i], 32);
#pragma unroll
        for (int s2 = 0; s2 < 2; ++s2) {
#pragma unroll
            for (int j = 0; j < 8; ++j) {
                int c = j & 3;
                float v;
                if (j < 4) v = (h == 0) ? p[c + 8 * s2] : pr[c + 8 * s2 + 4];
                else       v = (h == 1) ? p[c + 8 * s2 + 4] : pr[c + 8 * s2];
                unsigned ub = __float_as_uint(v);
                unsigned hb = ub & 0xffff0000u;
                float lo = v - __uint_as_float(hb);
                aPh[s2][j] = (short)(hb >> 16);
                aPl[s2][j] = (short)(__float_as_uint(lo) >> 16);
            }
        }
    }

    // ---- epilogue: flush PV(t_end-1) ----
    __syncthreads();
    {
        const int bl = (t_end - t_begin) & 1;
        const ushort_t* lVh = &lds[bl][2][0];
        const ushort_t* lVl = &lds[bl][3][0];
        if (resc_prev) {
#pragma unroll
            for (int i = 0; i < 16; ++i) {
                int rowq = (i & 3) + 8 * (i >> 2) + 4 * h;
                float a = __shfl(alpha_prev, rowq);
#pragma unroll
                for (int sub = 0; sub < 4; ++sub) O[sub][i] *= a;
            }
        }
#pragma unroll
        for (int sub = 0; sub < 4; ++sub) {
            const int vrow = (32 * sub + r) * 32;
#pragma unroll
            for (int s2 = 0; s2 < 2; ++s2) {
                int cc = (((2 * s2 + h) ^ (r & 3)) << 3);
                short8 bh = *(const short8*)&lVh[vrow + cc];
                short8 bl = *(const short8*)&lVl[vrow + cc];
                O[sub] = __builtin_amdgcn_mfma_f32_32x32x16_bf16(aPh[s2], bh, O[sub], 0, 0, 0);
                O[sub] = __builtin_amdgcn_mfma_f32_32x32x16_bf16(aPh[s2], bl, O[sub], 0, 0, 0);
                O[sub] = __builtin_amdgcn_mfma_f32_32x32x16_bf16(aPl[s2], bh, O[sub], 0, 0, 0);
            }
        }
    }

    lrun += __shfl_xor(lrun, 32);

    // ---- write partials ----
    float* Ob = Opart + (size_t)(sp * NHEADS + head) * NPAD * H;
#pragma unroll
    for (int i = 0; i < 16; ++i) {
        int rowq = (i & 3) + 8 * (i >> 2) + 4 * h;
        int qg = q0w + rowq;
        if (qg < N_NODES) {
            float* dst = &Ob[(size_t)qg * H + r];
#pragma unroll
            for (int sub = 0; sub < 4; ++sub) dst[32 * sub] = O[sub][i];
        }
    }
    if (h == 0 && q0w + r < N_NODES) {
        float2* ml = (float2*)mlpart;
        ml[(size_t)(sp * NHEADS + head) * NPAD + q0w + r] = make_float2(mrun, lrun);
    }
}

// ---------------- fused decoder MLP + split-K combine (8 nodes/block) ----------------
__global__ __launch_bounds__(256)
void decoder(const float* __restrict__ xr,
             const float* __restrict__ Opart, const float* __restrict__ mlpart, int ns,
             const float* __restrict__ Wd0, const float* __restrict__ bd0,
             const float* __restrict__ Wd, const float* __restrict__ bd,
             const float* __restrict__ Wout, const float* __restrict__ bout,
             float* __restrict__ out) {
    __shared__ float s0[8 * HCAT];
    __shared__ float s1[8 * H];
    __shared__ float s2[8 * H];
    int n0 = blockIdx.x * 8;
    int t = threadIdx.x;
    int f = t & (H - 1);
    int g = t >> 7;
    const float2* ml = (const float2*)mlpart;

    // cols 0:128 from xr
    for (int i = t; i < 8 * H; i += 256) {
        int n = i >> 7;
        s0[n * HCAT + (i & 127)] = xr[(size_t)(n0 + n) * H + (i & 127)];
    }
    // cols 128:640 via on-the-fly split-K combine
    for (int i = t; i < 8 * 512; i += 256) {
        int n = i >> 9;
        int rem = i & 511;
        int head = rem >> 7;
        int d = rem & 127;
        int q = n0 + n;
        float m = -1e30f;
        for (int s = 0; s < ns; ++s)
            m = fmaxf(m, ml[(size_t)(s * NHEADS + head) * NPAD + q].x);
        float lsum = 0.f, o = 0.f;
        for (int s = 0; s < ns; ++s) {
            float2 v = ml[(size_t)(s * NHEADS + head) * NPAD + q];
            float wgt = exp2f(v.x - m);
            lsum += v.y * wgt;
            o += Opart[((size_t)(s * NHEADS + head) * NPAD + q) * H + d] * wgt;
        }
        s0[n * HCAT + H + head * H + d] = o / lsum;
    }
    __syncthreads();

    float acc[4];
#pragma unroll
    for (int j = 0; j < 4; ++j) acc[j] = bd0[f];
    for (int d = 0; d < HCAT; ++d) {
        float w = Wd0[d * H + f];
#pragma unroll
        for (int j = 0; j < 4; ++j) acc[j] += s0[(g * 4 + j) * HCAT + d] * w;
    }
#pragma unroll
    for (int j = 0; j < 4; ++j) s1[(g * 4 + j) * H + f] = fmaxf(acc[j], 0.f);
    __syncthreads();

#pragma unroll
    for (int j = 0; j < 4; ++j) acc[j] = bd[f];
    for (int d = 0; d < H; ++d) {
        float w = Wd[d * H + f];
#pragma unroll
        for (int j = 0; j < 4; ++j) acc[j] += s1[(g * 4 + j) * H + d] * w;
    }
#pragma unroll
    for (int j = 0; j < 4; ++j) s2[(g * 4 + j) * H + f] = fmaxf(acc[j], 0.f);
    __syncthreads();

#pragma unroll
    for (int j = 0; j < 4; ++j) acc[j] = bd[H + f];
    for (int d = 0; d < H; ++d) {
        float w = Wd[H * H + d * H + f];
#pragma unroll
        for (int j = 0; j < 4; ++j) acc[j] += s2[(g * 4 + j) * H + d] * w;
    }
    __syncthreads();
#pragma unroll
    for (int j = 0; j < 4; ++j) s1[(g * 4 + j) * H + f] = fmaxf(acc[j], 0.f);
    __syncthreads();

    if (t < 24) {
        int n = t / 3, c = t % 3;
        float o = bout[c];
        for (int d = 0; d < H; ++d) o += s1[n * H + d] * Wout[d * 3 + c];
        out[(size_t)(n0 + n) * 3 + c] = o;
    }
}

// ---------------- launch ----------------
extern "C" void kernel_launch(void* const* d_in, const int* in_sizes, int n_in,
                              void* d_out, int out_size, void* d_ws, size_t ws_size,
                              hipStream_t stream) {
    const float* x_rest = (const float*)d_in[0];
    const float* x_rig  = (const float*)d_in[1];
    const int*   e_rest = (const int*)d_in[2];
    const int*   e_rig  = (const int*)d_in[3];
    const float* Wr0 = (const float*)d_in[4];
    const float* br0 = (const float*)d_in[5];
    const float* Wr  = (const float*)d_in[6];
    const float* br  = (const float*)d_in[7];
    const float* Wg0 = (const float*)d_in[8];
    const float* bg0 = (const float*)d_in[9];
    const float* Wg  = (const float*)d_in[10];
    const float* bg  = (const float*)d_in[11];
    const float* Wa  = (const float*)d_in[12];
    const float* ba  = (const float*)d_in[13];
    const float* Wd0 = (const float*)d_in[14];
    const float* bd0 = (const float*)d_in[15];
    const float* Wd  = (const float*)d_in[16];
    const float* bd  = (const float*)d_in[17];
    const float* Wout = (const float*)d_in[18];
    const float* bout = (const float*)d_in[19];
    float* out = (float*)d_out;

    const size_t NH = (size_t)N_NODES * H;
    float* ws = (float*)d_ws;
    float* dinv = ws;                      // 2N
    float* hw   = dinv + 2 * N_NODES;      // 2*NH
    float* hb   = hw + 2 * NH;             // 2*NH
    float* xr   = hb + 2 * NH;             // NH (resting L3 out; alias ha_r)
    float* hx   = xr + NH;                 // NH (alias ha_g)
    float* xg   = hb + NH;                 // alias hb_g: dead before L3 gather writes it
    float* xagg = hb;                      // alias hb: layer-1 staging (2 x 3N)
    ushort_t* Qh  = (ushort_t*)(hx + NH);
    ushort_t* Ql  = Qh + (size_t)NHEADS * N_NODES * H;
    ushort_t* Khs = Ql + (size_t)NHEADS * N_NODES * H;
    ushort_t* Kls = Khs + (size_t)NHEADS * NPAD * H;
    ushort_t* Vth = Kls + (size_t)NHEADS * NPAD * H;
    ushort_t* Vtl = Vth + (size_t)NTILES * H * 32;
    int* ib   = (int*)(Vtl + (size_t)NTILES * H * 32);
    int* cnt  = ib;                        // 2N
    int* cur  = cnt + 2 * N_NODES;         // 2N
    int* rs   = cur + 2 * N_NODES;         // 2(N+1)
    int* eslot = rs + 2 * (N_NODES + 1);   // 2E
    int* iend  = eslot + 2 * N_EDGES;
    float* Opart = (float*)(((uintptr_t)iend + 15) & ~(uintptr_t)15);

    size_t base_bytes = (size_t)((char*)Opart - (char*)d_ws);
    size_t per_split  = (size_t)NHEADS * NPAD * (H + 2) * sizeof(float);
    int NS = 2;
    if (ws_size >= base_bytes + 5 * per_split + (1u << 20)) NS = 5;
    else if (ws_size >= base_bytes + 4 * per_split + (1u << 20)) NS = 4;
    float* mlpart = Opart + (size_t)NS * NHEADS * NPAD * H;
    int tps = (NTILES + NS - 1) / NS;

    const int gN = (N_NODES + 255) / 256;
    const int gE = (N_EDGES + 255) / 256;

    // ---- CSR build (both graphs per launch) ----
    zero_ints<<<(4 * N_NODES + 255) / 256, 256, 0, stream>>>(cnt, 4 * N_NODES);
    hist2<<<dim3(gE, 2), 256, 0, stream>>>(e_rest, e_rig, cnt);
    scan2<<<2, 1024, 0, stream>>>(cnt, rs, dinv);
    place2<<<dim3(gE, 2), 256, 0, stream>>>(e_rest, e_rig, rs, cur, eslot);

    float* hw_r = hw, * hw_g = hw + NH;
    float* ha_r = xr, * ha_g = hx;
    float* hb_r = hb, * hb_g = hb + NH;
    float* xagg_r = xagg, * xagg_g = xagg + 3 * N_NODES;

    // L1 (reordered): aggregate 3-dim x, then GEMM 3->128 with fused bias+relu
    gather_x3<<<dim3(gN, 2), 256, 0, stream>>>(x_rest, x_rig, e_rest, e_rig, eslot, rs,
                                               dinv, xagg_r, xagg_g);
    gcn_gemm2<<<dim3(N_NODES / 16, 2), 256, 0, stream>>>(xagg_r, xagg_g, Wr0, Wg0,
                                                         ha_r, ha_g, 3, br0, bg0, 1);
    // L2
    gcn_gemm2<<<dim3(N_NODES / 16, 2), 256, 0, stream>>>(ha_r, ha_g, Wr, Wg, hw_r, hw_g, H,
                                                         nullptr, nullptr, 0);
    gather2<<<dim3(N_NODES, 2), H, 0, stream>>>(e_rest, e_rig, eslot, rs, hw_r, hw_g, dinv,
                                                br, bg, hb_r, hb_g);
    // L3: resting -> xr (overwrites dead ha_r), rigid -> xg (=hb_g, dead)
    gcn_gemm2<<<dim3(N_NODES / 16, 2), 256, 0, stream>>>(hb_r, hb_g, Wr + H * H, Wg + H * H,
                                                         hw_r, hw_g, H, nullptr, nullptr, 0);
    gather2<<<dim3(N_NODES, 2), H, 0, stream>>>(e_rest, e_rig, eslot, rs, hw_r, hw_g, dinv,
                                                br + H, bg + H, xr, xg);

    // ---- attention ----
    qk_kernel2<<<dim3(N_NODES / 16, NHEADS), 256, 0, stream>>>(xr, xg, Wa, ba,
                                                               Qh, Ql, Khs, Kls);
    zero_pad_k<<<(NHEADS * 16 * H + 255) / 256, 256, 0, stream>>>(Khs, Kls);
    cvt_vt<<<NTILES, 128, 0, stream>>>(xg, Vth, Vtl);
    attn_mfma8<<<dim3(47, NHEADS, NS), 256, 0, stream>>>(Qh, Ql, Khs, Kls, Vth, Vtl,
                                                         Opart, mlpart, tps);

    // ---- decoder (with fused split-K combine) ----
    decoder<<<N_NODES / 8, 256, 0, stream>>>(xr, Opart, mlpart, NS,
                                             Wd0, bd0, Wd, bd, Wout, bout, out);
}

// Round 12
// 620.212 us; speedup vs baseline: 1.0723x; 1.0723x over previous
//
#include <hip/hip_runtime.h>
#include <math.h>

#define N_NODES 6000
#define N_EDGES 192000
#define H 128
#define NHEADS 4
#define HCAT 640
#define NPAD 6016       // K/partial arrays padded to 6016 rows
#define NTILES 188      // ceil(6000/32)

typedef unsigned short ushort_t;
typedef __attribute__((ext_vector_type(8))) short short8;
typedef __attribute__((ext_vector_type(16))) float f32x16;

__device__ __forceinline__ void bf16split(float x, ushort_t& hi, ushort_t& lo) {
    unsigned ub = __float_as_uint(x);
    unsigned hb = ub & 0xffff0000u;
    float l = x - __uint_as_float(hb);
    hi = (ushort_t)(hb >> 16);
    lo = (ushort_t)(__float_as_uint(l) >> 16);
}

__device__ __forceinline__ void gll16(const ushort_t* g, ushort_t* l) {
    __builtin_amdgcn_global_load_lds((const __attribute__((address_space(1))) void*)g,
                                     (__attribute__((address_space(3))) void*)l, 16, 0, 0);
}

// ---------------- CSR build (both graphs per launch) ----------------
__global__ void zero_ints(int* p, int n) {
    int i = blockIdx.x * 256 + threadIdx.x;
    if (i < n) p[i] = 0;
}

__global__ void hist2(const int* __restrict__ eA, const int* __restrict__ eB,
                      int* __restrict__ cnt) {
    int e = blockIdx.x * 256 + threadIdx.x;
    int z = blockIdx.y;
    const int* edges = z ? eB : eA;
    if (e < N_EDGES) atomicAdd(&cnt[z * N_NODES + edges[N_EDGES + e]], 1);
}

// grid 2, 1024 threads: exclusive prefix over 6000 counts + dinv
__global__ __launch_bounds__(1024)
void scan2(const int* __restrict__ cnt_all, int* __restrict__ rs_all,
           float* __restrict__ dinv_all) {
    __shared__ int ps[1024];
    int z = blockIdx.x;
    const int* cnt = cnt_all + z * N_NODES;
    int* row_start = rs_all + z * (N_NODES + 1);
    float* dinv = dinv_all + z * N_NODES;
    int t = threadIdx.x;
    int base = t * 6;
    int local[6];
    int s = 0;
#pragma unroll
    for (int j = 0; j < 6; ++j) {
        int idx = base + j;
        int v = (idx < N_NODES) ? cnt[idx] : 0;
        local[j] = s;
        s += v;
        if (idx < N_NODES) dinv[idx] = rsqrtf((float)(v + 1));
    }
    ps[t] = s;
    __syncthreads();
    for (int off = 1; off < 1024; off <<= 1) {
        int v = (t >= off) ? ps[t - off] : 0;
        __syncthreads();
        ps[t] += v;
        __syncthreads();
    }
    int ex = (t > 0) ? ps[t - 1] : 0;
#pragma unroll
    for (int j = 0; j < 6; ++j) {
        int idx = base + j;
        if (idx < N_NODES) row_start[idx] = ex + local[j];
    }
    if (t == 1023) row_start[N_NODES] = ps[1023];
}

__global__ void place2(const int* __restrict__ eA, const int* __restrict__ eB,
                       const int* __restrict__ rs_all, int* __restrict__ cur_all,
                       int* __restrict__ eslot_all) {
    int e = blockIdx.x * 256 + threadIdx.x;
    int z = blockIdx.y;
    const int* edges = z ? eB : eA;
    if (e < N_EDGES) {
        int tg = edges[N_EDGES + e];
        int p = atomicAdd(&cur_all[z * N_NODES + tg], 1);
        eslot_all[(size_t)z * N_EDGES + rs_all[z * (N_NODES + 1) + tg] + p] = e;
    }
}

// ---------------- layer-1 reorder: aggregate raw 3-dim x first ----------------
__global__ __launch_bounds__(256)
void gather_x3(const float* __restrict__ xA, const float* __restrict__ xB,
               const int* __restrict__ eA, const int* __restrict__ eB,
               const int* __restrict__ eslot_all, const int* __restrict__ rs_all,
               const float* __restrict__ dinv_all,
               float* __restrict__ outA, float* __restrict__ outB) {
    int z = blockIdx.y;
    int n = blockIdx.x * 256 + threadIdx.x;
    if (n >= N_NODES) return;
    const int* edges = z ? eB : eA;
    const int* eslot = eslot_all + (size_t)z * N_EDGES;
    const int* row_start = rs_all + z * (N_NODES + 1);
    const float* x = z ? xB : xA;
    const float* dv = dinv_all + z * N_NODES;
    float* out = z ? outB : outA;
    float di = dv[n];
    float a0 = x[n * 3 + 0] * di * di;
    float a1 = x[n * 3 + 1] * di * di;
    float a2 = x[n * 3 + 2] * di * di;
    int s0 = row_start[n], s1 = row_start[n + 1];
    for (int i = s0; i < s1; ++i) {
        int e = eslot[i];
        int s = edges[e];
        float nr = dv[s] * di;
        a0 += x[s * 3 + 0] * nr;
        a1 += x[s * 3 + 1] * nr;
        a2 += x[s * 3 + 2] * nr;
    }
    out[n * 3 + 0] = a0; out[n * 3 + 1] = a1; out[n * 3 + 2] = a2;
}

// ---------------- GCN pieces (both graphs per launch) ----------------
__global__ __launch_bounds__(256)
void gcn_gemm2(const float* __restrict__ hinA, const float* __restrict__ hinB,
               const float* __restrict__ WA, const float* __restrict__ WB,
               float* __restrict__ hwA, float* __restrict__ hwB, int in_dim,
               const float* __restrict__ bA, const float* __restrict__ bB, int do_relu) {
    __shared__ float xs[16 * H];
    int z = blockIdx.y;
    const float* hin = z ? hinB : hinA;
    const float* W = z ? WB : WA;
    float* hw = z ? hwB : hwA;
    const float* b = z ? bB : bA;
    int n0 = blockIdx.x * 16;
    int t = threadIdx.x;
    int f = t & (H - 1);
    int g = t >> 7;
    for (int i = t; i < 16 * H; i += 256) {
        int r = i >> 7, c = i & (H - 1);
        xs[i] = (c < in_dim) ? hin[(size_t)(n0 + r) * in_dim + c] : 0.f;
    }
    __syncthreads();
    float acc[8];
#pragma unroll
    for (int j = 0; j < 8; ++j) acc[j] = 0.f;
    for (int d = 0; d < in_dim; ++d) {
        float w = W[d * H + f];
#pragma unroll
        for (int j = 0; j < 8; ++j) acc[j] += xs[(g * 8 + j) * H + d] * w;
    }
    if (do_relu) {
        float bias = b[f];
#pragma unroll
        for (int j = 0; j < 8; ++j)
            hw[(size_t)(n0 + g * 8 + j) * H + f] = fmaxf(acc[j] + bias, 0.f);
    } else {
#pragma unroll
        for (int j = 0; j < 8; ++j) hw[(size_t)(n0 + g * 8 + j) * H + f] = acc[j];
    }
}

__global__ __launch_bounds__(H)
void gather2(const int* __restrict__ eA, const int* __restrict__ eB,
             const int* __restrict__ eslot_all, const int* __restrict__ rs_all,
             const float* __restrict__ hwA, const float* __restrict__ hwB,
             const float* __restrict__ dinv_all,
             const float* __restrict__ bA, const float* __restrict__ bB,
             float* __restrict__ outA, float* __restrict__ outB, int osA, int osB) {
    __shared__ int ssrc[128];
    __shared__ float snrm[128];
    int z = blockIdx.y;
    const int* edges = z ? eB : eA;
    const int* eslot = eslot_all + (size_t)z * N_EDGES;
    const int* row_start = rs_all + z * (N_NODES + 1);
    const float* hw = z ? hwB : hwA;
    const float* dinv = dinv_all + z * N_NODES;
    const float* b = z ? bB : bA;
    float* out = z ? outB : outA;
    int ostride = z ? osB : osA;

    int tg = blockIdx.x, f = threadIdx.x;
    int s0 = row_start[tg], s1 = row_start[tg + 1];
    float di = dinv[tg];
    float acc = hw[(size_t)tg * H + f] * di * di;
    for (int base = s0; base < s1; base += 128) {
        int cnt = min(128, s1 - base);
        __syncthreads();
        if (f < cnt) {
            int e = eslot[base + f];
            int s = edges[e];
            ssrc[f] = s;
            snrm[f] = dinv[s] * di;
        }
        __syncthreads();
        for (int i = 0; i < cnt; ++i)
            acc += hw[(size_t)ssrc[i] * H + f] * snrm[i];
    }
    float v = acc + b[f];
    out[(size_t)tg * ostride + f] = v > 0.f ? v : 0.f;
}

// ---------------- merged q/k projection ----------------
__global__ __launch_bounds__(256)
void qk_kernel2(const float* __restrict__ qs, int qstride, const float* __restrict__ xg,
                const float* __restrict__ Wa, const float* __restrict__ ba,
                ushort_t* __restrict__ Qh, ushort_t* __restrict__ Ql,
                ushort_t* __restrict__ Khs, ushort_t* __restrict__ Kls) {
    __shared__ float xs[2][16][H];
    int n0 = blockIdx.x * 16, head = blockIdx.y;
    int t = threadIdx.x;
    int f = t & (H - 1);
    int g = t >> 7;
    for (int i = t; i < 2 * 16 * H; i += 256) {
        int which = i >> 11;
        int rem = i & 2047;
        int row = rem >> 7, col = rem & 127;
        xs[which][row][col] = which ? xg[(size_t)(n0 + row) * H + col]
                                    : qs[(size_t)(n0 + row) * qstride + col];
    }
    __syncthreads();
    const float* W = Wa + (size_t)head * H * H;
    float bias = ba[head * H + f];
    float acc[16];
#pragma unroll
    for (int j = 0; j < 16; ++j) acc[j] = bias;
    for (int d = 0; d < H; ++d) {
        float w = W[d * H + f];
#pragma unroll
        for (int j = 0; j < 16; ++j) acc[j] += xs[g][j][d] * w;
    }
#pragma unroll
    for (int j = 0; j < 16; ++j) {
        int n = n0 + j;
        ushort_t hi, lo;
        bf16split(acc[j], hi, lo);
        if (g == 0) {
            size_t idx = ((size_t)(head * N_NODES + n) << 7) + f;
            Qh[idx] = hi; Ql[idx] = lo;
        } else {
            int pos = (((f >> 3) ^ (n & 15)) << 3) + (f & 7);
            size_t idx = ((size_t)(head * NPAD + n) << 7) + pos;
            Khs[idx] = hi; Kls[idx] = lo;
        }
    }
}

__global__ void zero_pad_k(ushort_t* __restrict__ Khs, ushort_t* __restrict__ Kls) {
    int i = blockIdx.x * 256 + threadIdx.x;
    if (i < NHEADS * 16 * H) {
        int head = i / (16 * H);
        int rest = i - head * 16 * H;
        int n = N_NODES + (rest >> 7);
        int f = rest & 127;
        size_t idx = ((size_t)(head * NPAD + n) << 7) + f;
        Khs[idx] = 0; Kls[idx] = 0;
    }
}

// ---------------- V transpose -> tiled swizzled bf16 hi/lo ----------------
__global__ __launch_bounds__(128)
void cvt_vt(const float* __restrict__ xg, ushort_t* __restrict__ Vth, ushort_t* __restrict__ Vtl) {
    __shared__ float vs[32][129];
    int t0 = blockIdx.x;
    int t = threadIdx.x;
    for (int c = t; c < 32 * 32; c += 128) {
        int row = c >> 5, col4 = (c & 31) << 2;
        int n = t0 * 32 + row;
        float4 v = (n < N_NODES) ? *(const float4*)&xg[(size_t)n * H + col4]
                                 : float4{0.f, 0.f, 0.f, 0.f};
        vs[row][col4 + 0] = v.x; vs[row][col4 + 1] = v.y;
        vs[row][col4 + 2] = v.z; vs[row][col4 + 3] = v.w;
    }
    __syncthreads();
    int d = t;
    size_t base = ((size_t)t0 * H + d) * 32;
#pragma unroll
    for (int oc = 0; oc < 4; ++oc) {
        int cc = oc ^ (d & 3);
        unsigned uh[4], ul[4];
#pragma unroll
        for (int j = 0; j < 4; ++j) {
            ushort_t h0, l0, h1, l1;
            bf16split(vs[cc * 8 + 2 * j][d], h0, l0);
            bf16split(vs[cc * 8 + 2 * j + 1][d], h1, l1);
            uh[j] = (unsigned)h0 | ((unsigned)h1 << 16);
            ul[j] = (unsigned)l0 | ((unsigned)l1 << 16);
        }
        *(uint4*)&Vth[base + oc * 8] = make_uint4(uh[0], uh[1], uh[2], uh[3]);
        *(uint4*)&Vtl[base + oc * 8] = make_uint4(ul[0], ul[1], ul[2], ul[3]);
    }
}

// ---------------- MFMA flash attention: deferred PV + 3-way split S-accumulators ----------------
// grid (47, NHEADS, NS), block 256 = 4 waves; wave w owns q rows bx*128+w*32..+31.
// KEY FIX vs R5-R10: the S-phase previously chained all 24 MFMAs through ONE
// accumulator (24 x ~25-cyc dependent latency = the 41% MfmaUtil ceiling). Three
// independent accumulators (one per bf16x2 product term) cut chain depth to 8 and,
// with the 4 independent deferred-PV chains, give 7 concurrent MFMA streams.
__global__ __launch_bounds__(256, 2)
void attn_mfma9(const ushort_t* __restrict__ Qh, const ushort_t* __restrict__ Ql,
                const ushort_t* __restrict__ Khs, const ushort_t* __restrict__ Kls,
                const ushort_t* __restrict__ Vth, const ushort_t* __restrict__ Vtl,
                float* __restrict__ Opart, float* __restrict__ mlpart, int tps) {
    __shared__ ushort_t lds[2][4][4096];   // [buf][Kh,Kl,Vh,Vl] 64 KB
    const int head = blockIdx.y;
    const int sp = blockIdx.z;
    const int t = threadIdx.x;
    const int lane = t & 63;
    const int w = t >> 6;
    const int r = lane & 31;
    const int h = lane >> 5;
    const int q0w = blockIdx.x * 128 + w * 32;

    int t_begin = sp * tps;
    int t_end = t_begin + tps; if (t_end > NTILES) t_end = NTILES;

    const size_t kbase = (size_t)head * NPAD * H;
    const int o1 = t * 8, o2 = t * 8 + 2048;

    // Q B-fragments in registers
    int qr = q0w + r; if (qr > N_NODES - 1) qr = N_NODES - 1;
    const size_t qbase = ((size_t)(head * N_NODES + qr)) << 7;
    short8 qfh[8], qfl[8];
#pragma unroll
    for (int s = 0; s < 8; ++s) {
        qfh[s] = *(const short8*)&Qh[qbase + 16 * s + 8 * h];
        qfl[s] = *(const short8*)&Ql[qbase + 16 * s + 8 * h];
    }

    f32x16 O[4];
#pragma unroll
    for (int sub = 0; sub < 4; ++sub)
#pragma unroll
        for (int i = 0; i < 16; ++i) O[sub][i] = 0.f;
    float mrun = -1e30f, lrun = 0.f;
    short8 aPh[2], aPl[2];             // P(it-1) A-frags, consumed one iter later
    float alpha_prev = 1.f;
    int resc_prev = 0;

    // prologue: stage K(t_begin) into buf 0
    {
        const ushort_t* sKh = Khs + kbase + (size_t)t_begin * 4096;
        const ushort_t* sKl = Kls + kbase + (size_t)t_begin * 4096;
        gll16(sKh + o1, &lds[0][0][o1]); gll16(sKh + o2, &lds[0][0][o2]);
        gll16(sKl + o1, &lds[0][1][o1]); gll16(sKl + o2, &lds[0][1][o2]);
    }

    for (int it = t_begin; it < t_end; ++it) {
        const int b = (it - t_begin) & 1;
        __syncthreads();   // buf[b] = K(it), V(it-1) staged; prior buf[b^1] reads done
        {   // prefetch K(it+1) and V(it) into buf[b^1]
            int nt = it + 1; if (nt >= t_end) nt = t_begin;
            const ushort_t* sKh = Khs + kbase + (size_t)nt * 4096;
            const ushort_t* sKl = Kls + kbase + (size_t)nt * 4096;
            const ushort_t* sVh = Vth + (size_t)it * 4096;
            const ushort_t* sVl = Vtl + (size_t)it * 4096;
            gll16(sKh + o1, &lds[b ^ 1][0][o1]); gll16(sKh + o2, &lds[b ^ 1][0][o2]);
            gll16(sKl + o1, &lds[b ^ 1][1][o1]); gll16(sKl + o2, &lds[b ^ 1][1][o2]);
            gll16(sVh + o1, &lds[b ^ 1][2][o1]); gll16(sVh + o2, &lds[b ^ 1][2][o2]);
            gll16(sVl + o1, &lds[b ^ 1][3][o1]); gll16(sVl + o2, &lds[b ^ 1][3][o2]);
        }
        const ushort_t* lKh = &lds[b][0][0];
        const ushort_t* lKl = &lds[b][1][0];
        const ushort_t* lVh = &lds[b][2][0];   // V(it-1)
        const ushort_t* lVl = &lds[b][3][0];

        // ---- S^T(it): 3 independent 8-deep MFMA chains (one per product term) ----
        f32x16 accA, accB, accC;
#pragma unroll
        for (int i = 0; i < 16; ++i) { accA[i] = 0.f; accB[i] = 0.f; accC[i] = 0.f; }
        const int krow = r * H;
#pragma unroll
        for (int s = 0; s < 8; ++s) {
            int cc = ((2 * s + h) ^ (r & 15)) << 3;
            short8 ah = *(const short8*)&lKh[krow + cc];
            short8 al = *(const short8*)&lKl[krow + cc];
            accA = __builtin_amdgcn_mfma_f32_32x32x16_bf16(ah, qfh[s], accA, 0, 0, 0);
            accB = __builtin_amdgcn_mfma_f32_32x32x16_bf16(ah, qfl[s], accB, 0, 0, 0);
            accC = __builtin_amdgcn_mfma_f32_32x32x16_bf16(al, qfh[s], accC, 0, 0, 0);
        }

        // ---- deferred PV(it-1): 4 more independent chains, overlaps S + softmax ----
        if (it != t_begin) {
            if (resc_prev) {
#pragma unroll
                for (int i = 0; i < 16; ++i) {
                    int rowq = (i & 3) + 8 * (i >> 2) + 4 * h;
                    float a = __shfl(alpha_prev, rowq);
#pragma unroll
                    for (int sub = 0; sub < 4; ++sub) O[sub][i] *= a;
                }
            }
#pragma unroll
            for (int sub = 0; sub < 4; ++sub) {
                const int vrow = (32 * sub + r) * 32;
#pragma unroll
                for (int s2 = 0; s2 < 2; ++s2) {
                    int cc = (((2 * s2 + h) ^ (r & 3)) << 3);
                    short8 bh = *(const short8*)&lVh[vrow + cc];
                    short8 bl = *(const short8*)&lVl[vrow + cc];
                    O[sub] = __builtin_amdgcn_mfma_f32_32x32x16_bf16(aPh[s2], bh, O[sub], 0, 0, 0);
                    O[sub] = __builtin_amdgcn_mfma_f32_32x32x16_bf16(aPh[s2], bl, O[sub], 0, 0, 0);
                    O[sub] = __builtin_amdgcn_mfma_f32_32x32x16_bf16(aPl[s2], bh, O[sub], 0, 0, 0);
                }
            }
        }

        // ---- online softmax(it) ----
        float sv[16];
#pragma unroll
        for (int i = 0; i < 16; ++i) sv[i] = accA[i] + accB[i] + accC[i];
        int klim = N_NODES - (it << 5);
        if (klim < 32) {
#pragma unroll
            for (int i = 0; i < 16; ++i) {
                int row = (i & 3) + 8 * (i >> 2) + 4 * h;
                if (row >= klim) sv[i] = -1e30f;
            }
        }
        float tmax = sv[0];
#pragma unroll
        for (int i = 1; i < 16; ++i) tmax = fmaxf(tmax, sv[i]);
        tmax = fmaxf(tmax, __shfl_xor(tmax, 32));
        float mnew = fmaxf(mrun, tmax);
        float p[16];
        float psum = 0.f;
#pragma unroll
        for (int i = 0; i < 16; ++i) { p[i] = __expf(sv[i] - mnew); psum += p[i]; }

        if (__ballot(mnew > mrun)) {
            float alpha = __expf(mrun - mnew);
            lrun *= alpha;
            alpha_prev = alpha;
            resc_prev = 1;
        } else {
            resc_prev = 0;
        }
        lrun += psum;
        mrun = mnew;

        // ---- P(it) repack -> A-operand frags for next iter ----
        float pr[16];
#pragma unroll
        for (int i = 0; i < 16; ++i) pr[i] = __shfl_xor(p[i], 32);
#pragma unroll
        for (int s2 = 0; s2 < 2; ++s2) {
#pragma unroll
            for (int j = 0; j < 8; ++j) {
                int c = j & 3;
                float v;
                if (j < 4) v = (h == 0) ? p[c + 8 * s2] : pr[c + 8 * s2 + 4];
                else       v = (h == 1) ? p[c + 8 * s2 + 4] : pr[c + 8 * s2];
                unsigned ub = __float_as_uint(v);
                unsigned hb = ub & 0xffff0000u;
                float lo = v - __uint_as_float(hb);
                aPh[s2][j] = (short)(hb >> 16);
                aPl[s2][j] = (short)(__float_as_uint(lo) >> 16);
            }
        }
    }

    // ---- epilogue: flush PV(t_end-1) from the last-prefetched buffer ----
    __syncthreads();   // V(t_end-1) staging drained
    {
        const int bl = (t_end - t_begin) & 1;
        const ushort_t* lVh = &lds[bl][2][0];
        const ushort_t* lVl = &lds[bl][3][0];
        if (resc_prev) {
#pragma unroll
            for (int i = 0; i < 16; ++i) {
                int rowq = (i & 3) + 8 * (i >> 2) + 4 * h;
                float a = __shfl(alpha_prev, rowq);
#pragma unroll
                for (int sub = 0; sub < 4; ++sub) O[sub][i] *= a;
            }
        }
#pragma unroll
        for (int sub = 0; sub < 4; ++sub) {
            const int vrow = (32 * sub + r) * 32;
#pragma unroll
            for (int s2 = 0; s2 < 2; ++s2) {
                int cc = (((2 * s2 + h) ^ (r & 3)) << 3);
                short8 bh = *(const short8*)&lVh[vrow + cc];
                short8 bl = *(const short8*)&lVl[vrow + cc];
                O[sub] = __builtin_amdgcn_mfma_f32_32x32x16_bf16(aPh[s2], bh, O[sub], 0, 0, 0);
                O[sub] = __builtin_amdgcn_mfma_f32_32x32x16_bf16(aPh[s2], bl, O[sub], 0, 0, 0);
                O[sub] = __builtin_amdgcn_mfma_f32_32x32x16_bf16(aPl[s2], bh, O[sub], 0, 0, 0);
            }
        }
    }

    lrun += __shfl_xor(lrun, 32);   // deferred cross-half l sum

    // ---- write partials (guard q >= N_NODES) ----
    float* Ob = Opart + (size_t)(sp * NHEADS + head) * NPAD * H;
#pragma unroll
    for (int i = 0; i < 16; ++i) {
        int rowq = (i & 3) + 8 * (i >> 2) + 4 * h;
        int qg = q0w + rowq;
        if (qg < N_NODES) {
            float* dst = &Ob[(size_t)qg * H + r];
#pragma unroll
            for (int sub = 0; sub < 4; ++sub) dst[32 * sub] = O[sub][i];
        }
    }
    if (h == 0 && q0w + r < N_NODES) {
        float2* ml = (float2*)mlpart;
        ml[(size_t)(sp * NHEADS + head) * NPAD + q0w + r] = make_float2(mrun, lrun);
    }
}

// merge split-K partials into hcat (float4)
__global__ __launch_bounds__(256)
void attn_combine(const float* __restrict__ Opart, const float* __restrict__ mlpart,
                  float* __restrict__ hcat, int ns) {
    int idx = blockIdx.x * 256 + threadIdx.x;
    if (idx >= NHEADS * N_NODES * (H / 4)) return;
    int head = idx / (N_NODES * (H / 4));
    int rest = idx - head * N_NODES * (H / 4);
    int q = rest >> 5;
    int d4 = (rest & 31) << 2;
    const float2* ml = (const float2*)mlpart;
    float m = -1e30f;
    for (int s = 0; s < ns; ++s)
        m = fmaxf(m, ml[(size_t)(s * NHEADS + head) * NPAD + q].x);
    float lsum = 0.f;
    float4 o = {0.f, 0.f, 0.f, 0.f};
    for (int s = 0; s < ns; ++s) {
        float2 v = ml[(size_t)(s * NHEADS + head) * NPAD + q];
        float wgt = __expf(v.x - m);
        lsum += v.y * wgt;
        float4 ov = *(const float4*)&Opart[((size_t)(s * NHEADS + head) * NPAD + q) * H + d4];
        o.x += ov.x * wgt; o.y += ov.y * wgt; o.z += ov.z * wgt; o.w += ov.w * wgt;
    }
    float inv = 1.f / lsum;
    float4 res = {o.x * inv, o.y * inv, o.z * inv, o.w * inv};
    *(float4*)&hcat[(size_t)q * HCAT + H + head * H + d4] = res;
}

// ---------------- fused decoder MLP (8 nodes/block) ----------------
__global__ __launch_bounds__(256)
void decoder(const float* __restrict__ hcat,
             const float* __restrict__ Wd0, const float* __restrict__ bd0,
             const float* __restrict__ Wd, const float* __restrict__ bd,
             const float* __restrict__ Wout, const float* __restrict__ bout,
             float* __restrict__ out) {
    __shared__ float s0[8 * HCAT];
    __shared__ float s1[8 * H];
    __shared__ float s2[8 * H];
    int n0 = blockIdx.x * 8;
    int t = threadIdx.x;
    int f = t & (H - 1);
    int g = t >> 7;
    for (int i = t; i < 8 * HCAT; i += 256)
        s0[i] = hcat[(size_t)n0 * HCAT + i];
    __syncthreads();

    float acc[4];
#pragma unroll
    for (int j = 0; j < 4; ++j) acc[j] = bd0[f];
    for (int d = 0; d < HCAT; ++d) {
        float w = Wd0[d * H + f];
#pragma unroll
        for (int j = 0; j < 4; ++j) acc[j] += s0[(g * 4 + j) * HCAT + d] * w;
    }
#pragma unroll
    for (int j = 0; j < 4; ++j) s1[(g * 4 + j) * H + f] = fmaxf(acc[j], 0.f);
    __syncthreads();

#pragma unroll
    for (int j = 0; j < 4; ++j) acc[j] = bd[f];
    for (int d = 0; d < H; ++d) {
        float w = Wd[d * H + f];
#pragma unroll
        for (int j = 0; j < 4; ++j) acc[j] += s1[(g * 4 + j) * H + d] * w;
    }
#pragma unroll
    for (int j = 0; j < 4; ++j) s2[(g * 4 + j) * H + f] = fmaxf(acc[j], 0.f);
    __syncthreads();

#pragma unroll
    for (int j = 0; j < 4; ++j) acc[j] = bd[H + f];
    for (int d = 0; d < H; ++d) {
        float w = Wd[H * H + d * H + f];
#pragma unroll
        for (int j = 0; j < 4; ++j) acc[j] += s2[(g * 4 + j) * H + d] * w;
    }
    __syncthreads();
#pragma unroll
    for (int j = 0; j < 4; ++j) s1[(g * 4 + j) * H + f] = fmaxf(acc[j], 0.f);
    __syncthreads();

    if (t < 24) {
        int n = t / 3, c = t % 3;
        float o = bout[c];
        for (int d = 0; d < H; ++d) o += s1[n * H + d] * Wout[d * 3 + c];
        out[(size_t)(n0 + n) * 3 + c] = o;
    }
}

// ---------------- launch ----------------
extern "C" void kernel_launch(void* const* d_in, const int* in_sizes, int n_in,
                              void* d_out, int out_size, void* d_ws, size_t ws_size,
                              hipStream_t stream) {
    const float* x_rest = (const float*)d_in[0];
    const float* x_rig  = (const float*)d_in[1];
    const int*   e_rest = (const int*)d_in[2];
    const int*   e_rig  = (const int*)d_in[3];
    const float* Wr0 = (const float*)d_in[4];
    const float* br0 = (const float*)d_in[5];
    const float* Wr  = (const float*)d_in[6];
    const float* br  = (const float*)d_in[7];
    const float* Wg0 = (const float*)d_in[8];
    const float* bg0 = (const float*)d_in[9];
    const float* Wg  = (const float*)d_in[10];
    const float* bg  = (const float*)d_in[11];
    const float* Wa  = (const float*)d_in[12];
    const float* ba  = (const float*)d_in[13];
    const float* Wd0 = (const float*)d_in[14];
    const float* bd0 = (const float*)d_in[15];
    const float* Wd  = (const float*)d_in[16];
    const float* bd  = (const float*)d_in[17];
    const float* Wout = (const float*)d_in[18];
    const float* bout = (const float*)d_in[19];
    float* out = (float*)d_out;

    const size_t NH = (size_t)N_NODES * H;
    float* ws = (float*)d_ws;
    float* dinv = ws;                      // 2N
    float* hw   = dinv + 2 * N_NODES;      // 2*NH
    float* hb   = hw + 2 * NH;             // 2*NH
    float* hcat = hb + 2 * NH;             // N*HCAT
    float* ha   = hcat;                    // alias: dead before hcat is written
    float* xg   = hb + NH;                 // alias hb_g: dead before L3 gather writes it
    float* xagg = hb;                      // alias hb: layer-1 staging (2 x 3N)
    ushort_t* Qh  = (ushort_t*)(hcat + (size_t)N_NODES * HCAT);
    ushort_t* Ql  = Qh + (size_t)NHEADS * N_NODES * H;
    ushort_t* Khs = Ql + (size_t)NHEADS * N_NODES * H;
    ushort_t* Kls = Khs + (size_t)NHEADS * NPAD * H;
    ushort_t* Vth = Kls + (size_t)NHEADS * NPAD * H;
    ushort_t* Vtl = Vth + (size_t)NTILES * H * 32;
    int* ib   = (int*)(Vtl + (size_t)NTILES * H * 32);
    int* cnt  = ib;                        // 2N
    int* cur  = cnt + 2 * N_NODES;         // 2N
    int* rs   = cur + 2 * N_NODES;         // 2(N+1)
    int* eslot = rs + 2 * (N_NODES + 1);   // 2E
    int* iend  = eslot + 2 * N_EDGES;
    float* Opart = (float*)(((uintptr_t)iend + 15) & ~(uintptr_t)15);

    size_t base_bytes = (size_t)((char*)Opart - (char*)d_ws);
    size_t per_split  = (size_t)NHEADS * NPAD * (H + 2) * sizeof(float);
    int NS = 2;
    if (ws_size >= base_bytes + 5 * per_split + (1u << 20)) NS = 5;
    else if (ws_size >= base_bytes + 4 * per_split + (1u << 20)) NS = 4;
    float* mlpart = Opart + (size_t)NS * NHEADS * NPAD * H;
    int tps = (NTILES + NS - 1) / NS;

    const int gN = (N_NODES + 255) / 256;
    const int gE = (N_EDGES + 255) / 256;

    // ---- CSR build (both graphs per launch) ----
    zero_ints<<<(4 * N_NODES + 255) / 256, 256, 0, stream>>>(cnt, 4 * N_NODES);
    hist2<<<dim3(gE, 2), 256, 0, stream>>>(e_rest, e_rig, cnt);
    scan2<<<2, 1024, 0, stream>>>(cnt, rs, dinv);
    place2<<<dim3(gE, 2), 256, 0, stream>>>(e_rest, e_rig, rs, cur, eslot);

    float* hw_r = hw, * hw_g = hw + NH;
    float* ha_r = ha, * ha_g = ha + NH;
    float* hb_r = hb, * hb_g = hb + NH;
    float* xagg_r = xagg, * xagg_g = xagg + 3 * N_NODES;

    // L1 (reordered): aggregate 3-dim x, then GEMM 3->128 with fused bias+relu
    gather_x3<<<dim3(gN, 2), 256, 0, stream>>>(x_rest, x_rig, e_rest, e_rig, eslot, rs,
                                               dinv, xagg_r, xagg_g);
    gcn_gemm2<<<dim3(N_NODES / 16, 2), 256, 0, stream>>>(xagg_r, xagg_g, Wr0, Wg0,
                                                         ha_r, ha_g, 3, br0, bg0, 1);
    // L2
    gcn_gemm2<<<dim3(N_NODES / 16, 2), 256, 0, stream>>>(ha_r, ha_g, Wr, Wg, hw_r, hw_g, H,
                                                         nullptr, nullptr, 0);
    gather2<<<dim3(N_NODES, 2), H, 0, stream>>>(e_rest, e_rig, eslot, rs, hw_r, hw_g, dinv,
                                                br, bg, hb_r, hb_g, H, H);
    // L3: resting -> hcat cols 0:128 (stride 640); rigid -> xg (stride 128)
    gcn_gemm2<<<dim3(N_NODES / 16, 2), 256, 0, stream>>>(hb_r, hb_g, Wr + H * H, Wg + H * H,
                                                         hw_r, hw_g, H, nullptr, nullptr, 0);
    gather2<<<dim3(N_NODES, 2), H, 0, stream>>>(e_rest, e_rig, eslot, rs, hw_r, hw_g, dinv,
                                                br + H, bg + H, hcat, xg, HCAT, H);

    // ---- attention ----
    qk_kernel2<<<dim3(N_NODES / 16, NHEADS), 256, 0, stream>>>(hcat, HCAT, xg, Wa, ba,
                                                               Qh, Ql, Khs, Kls);
    zero_pad_k<<<(NHEADS * 16 * H + 255) / 256, 256, 0, stream>>>(Khs, Kls);
    cvt_vt<<<NTILES, 128, 0, stream>>>(xg, Vth, Vtl);
    attn_mfma9<<<dim3(47, NHEADS, NS), 256, 0, stream>>>(Qh, Ql, Khs, Kls, Vth, Vtl,
                                                         Opart, mlpart, tps);
    attn_combine<<<(NHEADS * N_NODES * (H / 4) + 255) / 256, 256, 0, stream>>>(Opart, mlpart,
                                                                               hcat, NS);

    // ---- decoder ----
    decoder<<<N_NODES / 8, 256, 0, stream>>>(hcat, Wd0, bd0, Wd, bd, Wout, bout, out);
}

// Round 13
// 569.719 us; speedup vs baseline: 1.1673x; 1.0886x over previous
//
#include <hip/hip_runtime.h>
#include <math.h>

#define N_NODES 6000
#define N_EDGES 192000
#define H 128
#define NHEADS 4
#define HCAT 640
#define NPAD 6016       // K/partial arrays padded to 6016 rows
#define NTILES 188      // ceil(6000/32)

typedef unsigned short ushort_t;
typedef __attribute__((ext_vector_type(8))) short short8;
typedef __attribute__((ext_vector_type(16))) float f32x16;

__device__ __forceinline__ void bf16split(float x, ushort_t& hi, ushort_t& lo) {
    unsigned ub = __float_as_uint(x);
    unsigned hb = ub & 0xffff0000u;
    float l = x - __uint_as_float(hb);
    hi = (ushort_t)(hb >> 16);
    lo = (ushort_t)(__float_as_uint(l) >> 16);
}

__device__ __forceinline__ void gll16(const ushort_t* g, ushort_t* l) {
    __builtin_amdgcn_global_load_lds((const __attribute__((address_space(1))) void*)g,
                                     (__attribute__((address_space(3))) void*)l, 16, 0, 0);
}

// ---------------- CSR build (both graphs per launch) ----------------
__global__ void zero_ints(int* p, int n) {
    int i = blockIdx.x * 256 + threadIdx.x;
    if (i < n) p[i] = 0;
}

__global__ void hist2(const int* __restrict__ eA, const int* __restrict__ eB,
                      int* __restrict__ cnt) {
    int e = blockIdx.x * 256 + threadIdx.x;
    int z = blockIdx.y;
    const int* edges = z ? eB : eA;
    if (e < N_EDGES) atomicAdd(&cnt[z * N_NODES + edges[N_EDGES + e]], 1);
}

__global__ __launch_bounds__(1024)
void scan2(const int* __restrict__ cnt_all, int* __restrict__ rs_all,
           float* __restrict__ dinv_all) {
    __shared__ int ps[1024];
    int z = blockIdx.x;
    const int* cnt = cnt_all + z * N_NODES;
    int* row_start = rs_all + z * (N_NODES + 1);
    float* dinv = dinv_all + z * N_NODES;
    int t = threadIdx.x;
    int base = t * 6;
    int local[6];
    int s = 0;
#pragma unroll
    for (int j = 0; j < 6; ++j) {
        int idx = base + j;
        int v = (idx < N_NODES) ? cnt[idx] : 0;
        local[j] = s;
        s += v;
        if (idx < N_NODES) dinv[idx] = rsqrtf((float)(v + 1));
    }
    ps[t] = s;
    __syncthreads();
    for (int off = 1; off < 1024; off <<= 1) {
        int v = (t >= off) ? ps[t - off] : 0;
        __syncthreads();
        ps[t] += v;
        __syncthreads();
    }
    int ex = (t > 0) ? ps[t - 1] : 0;
#pragma unroll
    for (int j = 0; j < 6; ++j) {
        int idx = base + j;
        if (idx < N_NODES) row_start[idx] = ex + local[j];
    }
    if (t == 1023) row_start[N_NODES] = ps[1023];
}

__global__ void place2(const int* __restrict__ eA, const int* __restrict__ eB,
                       const int* __restrict__ rs_all, int* __restrict__ cur_all,
                       int* __restrict__ eslot_all) {
    int e = blockIdx.x * 256 + threadIdx.x;
    int z = blockIdx.y;
    const int* edges = z ? eB : eA;
    if (e < N_EDGES) {
        int tg = edges[N_EDGES + e];
        int p = atomicAdd(&cur_all[z * N_NODES + tg], 1);
        eslot_all[(size_t)z * N_EDGES + rs_all[z * (N_NODES + 1) + tg] + p] = e;
    }
}

// ---------------- fused layer-1: aggregate raw 3-dim x + GEMM 3->128 + bias + relu ----------------
// grid (375, 2), block 256. Phase A: 16 threads/node accumulate edge contributions,
// shfl-reduce, add self loop. Phase B: GEMM with in_dim=3 from LDS.
__global__ __launch_bounds__(256)
void l1_fused(const float* __restrict__ xA, const float* __restrict__ xB,
              const int* __restrict__ eA, const int* __restrict__ eB,
              const int* __restrict__ eslot_all, const int* __restrict__ rs_all,
              const float* __restrict__ dinv_all,
              const float* __restrict__ WA, const float* __restrict__ WB,
              const float* __restrict__ bA, const float* __restrict__ bB,
              float* __restrict__ outA, float* __restrict__ outB) {
    __shared__ float xs[16][4];
    int z = blockIdx.y;
    const int* edges = z ? eB : eA;
    const int* eslot = eslot_all + (size_t)z * N_EDGES;
    const int* row_start = rs_all + z * (N_NODES + 1);
    const float* x = z ? xB : xA;
    const float* dv = dinv_all + z * N_NODES;
    const float* W = z ? WB : WA;
    const float* bb = z ? bB : bA;
    float* out = z ? outB : outA;
    int n0 = blockIdx.x * 16;
    int t = threadIdx.x;
    int ln = t >> 4, slot = t & 15;
    int n = n0 + ln;
    float di = dv[n];
    float a0 = 0.f, a1 = 0.f, a2 = 0.f;
    int s0 = row_start[n], s1 = row_start[n + 1];
    for (int i = s0 + slot; i < s1; i += 16) {
        int e = eslot[i];
        int s = edges[e];
        float nr = dv[s] * di;
        a0 += x[s * 3 + 0] * nr;
        a1 += x[s * 3 + 1] * nr;
        a2 += x[s * 3 + 2] * nr;
    }
#pragma unroll
    for (int off = 1; off < 16; off <<= 1) {
        a0 += __shfl_xor(a0, off);
        a1 += __shfl_xor(a1, off);
        a2 += __shfl_xor(a2, off);
    }
    if (slot == 0) {
        xs[ln][0] = a0 + x[n * 3 + 0] * di * di;
        xs[ln][1] = a1 + x[n * 3 + 1] * di * di;
        xs[ln][2] = a2 + x[n * 3 + 2] * di * di;
    }
    __syncthreads();
    int f = t & 127, g = t >> 7;
    float bias = bb[f];
    float w0 = W[0 * H + f], w1 = W[1 * H + f], w2 = W[2 * H + f];
#pragma unroll
    for (int j = 0; j < 8; ++j) {
        int node = g * 8 + j;
        float acc = bias + xs[node][0] * w0 + xs[node][1] * w1 + xs[node][2] * w2;
        out[(size_t)(n0 + node) * H + f] = fmaxf(acc, 0.f);
    }
}

// ---------------- GCN pieces (both graphs per launch) ----------------
__global__ __launch_bounds__(256)
void gcn_gemm2(const float* __restrict__ hinA, const float* __restrict__ hinB,
               const float* __restrict__ WA, const float* __restrict__ WB,
               float* __restrict__ hwA, float* __restrict__ hwB) {
    __shared__ float xs[16 * H];
    int z = blockIdx.y;
    const float* hin = z ? hinB : hinA;
    const float* W = z ? WB : WA;
    float* hw = z ? hwB : hwA;
    int n0 = blockIdx.x * 16;
    int t = threadIdx.x;
    int f = t & (H - 1);
    int g = t >> 7;
    for (int i = t; i < 16 * H; i += 256)
        xs[i] = hin[(size_t)n0 * H + i];
    __syncthreads();
    float acc[8];
#pragma unroll
    for (int j = 0; j < 8; ++j) acc[j] = 0.f;
    for (int d = 0; d < H; ++d) {
        float w = W[d * H + f];
#pragma unroll
        for (int j = 0; j < 8; ++j) acc[j] += xs[(g * 8 + j) * H + d] * w;
    }
#pragma unroll
    for (int j = 0; j < 8; ++j) hw[(size_t)(n0 + g * 8 + j) * H + f] = acc[j];
}

__global__ __launch_bounds__(H)
void gather2(const int* __restrict__ eA, const int* __restrict__ eB,
             const int* __restrict__ eslot_all, const int* __restrict__ rs_all,
             const float* __restrict__ hwA, const float* __restrict__ hwB,
             const float* __restrict__ dinv_all,
             const float* __restrict__ bA, const float* __restrict__ bB,
             float* __restrict__ outA, float* __restrict__ outB, int osA, int osB) {
    __shared__ int ssrc[128];
    __shared__ float snrm[128];
    int z = blockIdx.y;
    const int* edges = z ? eB : eA;
    const int* eslot = eslot_all + (size_t)z * N_EDGES;
    const int* row_start = rs_all + z * (N_NODES + 1);
    const float* hw = z ? hwB : hwA;
    const float* dinv = dinv_all + z * N_NODES;
    const float* b = z ? bB : bA;
    float* out = z ? outB : outA;
    int ostride = z ? osB : osA;

    int tg = blockIdx.x, f = threadIdx.x;
    int s0 = row_start[tg], s1 = row_start[tg + 1];
    float di = dinv[tg];
    float acc = hw[(size_t)tg * H + f] * di * di;
    for (int base = s0; base < s1; base += 128) {
        int cnt = min(128, s1 - base);
        __syncthreads();
        if (f < cnt) {
            int e = eslot[base + f];
            int s = edges[e];
            ssrc[f] = s;
            snrm[f] = dinv[s] * di;
        }
        __syncthreads();
        for (int i = 0; i < cnt; ++i)
            acc += hw[(size_t)ssrc[i] * H + f] * snrm[i];
    }
    float v = acc + b[f];
    out[(size_t)tg * ostride + f] = v > 0.f ? v : 0.f;
}

// ---------------- fused attn prep: qk projections + K pad zero + V transpose ----------------
// flat grid 1720 x 256: [0,1500) qk (head=bx/375); [1500,1688) cvt tile; [1688,1720) pad
__global__ __launch_bounds__(256)
void attn_prep(const float* __restrict__ qs, const float* __restrict__ xg,
               const float* __restrict__ Wa, const float* __restrict__ ba,
               ushort_t* __restrict__ Qh, ushort_t* __restrict__ Ql,
               ushort_t* __restrict__ Khs, ushort_t* __restrict__ Kls,
               ushort_t* __restrict__ Vth, ushort_t* __restrict__ Vtl) {
    __shared__ float smem[4224];
    int bx = blockIdx.x;
    int t = threadIdx.x;
    if (bx < 1500) {
        // ---- qk ----
        int head = bx / 375;
        int n0 = (bx - head * 375) * 16;
        float* xs = smem;   // [2][16][128]
        int f = t & (H - 1);
        int g = t >> 7;
        for (int i = t; i < 2 * 16 * H; i += 256) {
            int which = i >> 11;
            int rem = i & 2047;
            int row = rem >> 7, col = rem & 127;
            xs[i] = which ? xg[(size_t)(n0 + row) * H + col]
                          : qs[(size_t)(n0 + row) * HCAT + col];
        }
        __syncthreads();
        const float* W = Wa + (size_t)head * H * H;
        float bias = ba[head * H + f];
        float acc[16];
#pragma unroll
        for (int j = 0; j < 16; ++j) acc[j] = bias;
        for (int d = 0; d < H; ++d) {
            float w = W[d * H + f];
#pragma unroll
            for (int j = 0; j < 16; ++j) acc[j] += xs[g * 2048 + j * H + d] * w;
        }
#pragma unroll
        for (int j = 0; j < 16; ++j) {
            int n = n0 + j;
            ushort_t hi, lo;
            bf16split(acc[j], hi, lo);
            if (g == 0) {
                size_t idx = ((size_t)(head * N_NODES + n) << 7) + f;
                Qh[idx] = hi; Ql[idx] = lo;
            } else {
                int pos = (((f >> 3) ^ (n & 15)) << 3) + (f & 7);
                size_t idx = ((size_t)(head * NPAD + n) << 7) + pos;
                Khs[idx] = hi; Kls[idx] = lo;
            }
        }
    } else if (bx < 1688) {
        // ---- V transpose -> tiled swizzled bf16 hi/lo ----
        int t0 = bx - 1500;
        float (*vs)[129] = (float(*)[129])smem;
        for (int c = t; c < 32 * 32; c += 256) {
            int row = c >> 5, col4 = (c & 31) << 2;
            int n = t0 * 32 + row;
            float4 v = (n < N_NODES) ? *(const float4*)&xg[(size_t)n * H + col4]
                                     : float4{0.f, 0.f, 0.f, 0.f};
            vs[row][col4 + 0] = v.x; vs[row][col4 + 1] = v.y;
            vs[row][col4 + 2] = v.z; vs[row][col4 + 3] = v.w;
        }
        __syncthreads();
        int d = t & 127;
        int ocb = (t >> 7) * 2;
        size_t base = ((size_t)t0 * H + d) * 32;
#pragma unroll
        for (int oo = 0; oo < 2; ++oo) {
            int oc = ocb + oo;
            int cc = oc ^ (d & 3);
            unsigned uh[4], ul[4];
#pragma unroll
            for (int j = 0; j < 4; ++j) {
                ushort_t h0, l0, h1, l1;
                bf16split(vs[cc * 8 + 2 * j][d], h0, l0);
                bf16split(vs[cc * 8 + 2 * j + 1][d], h1, l1);
                uh[j] = (unsigned)h0 | ((unsigned)h1 << 16);
                ul[j] = (unsigned)l0 | ((unsigned)l1 << 16);
            }
            *(uint4*)&Vth[base + oc * 8] = make_uint4(uh[0], uh[1], uh[2], uh[3]);
            *(uint4*)&Vtl[base + oc * 8] = make_uint4(ul[0], ul[1], ul[2], ul[3]);
        }
    } else {
        // ---- zero pad K rows 6000..6015 ----
        int i = (bx - 1688) * 256 + t;
        if (i < NHEADS * 16 * H) {
            int head = i / (16 * H);
            int rest = i - head * 16 * H;
            int n = N_NODES + (rest >> 7);
            int f = rest & 127;
            size_t idx = ((size_t)(head * NPAD + n) << 7) + f;
            Khs[idx] = 0; Kls[idx] = 0;
        }
    }
}

// ---------------- MFMA flash attention: deferred PV woven with softmax VALU ----------------
// grid (47, NHEADS, NS), block 256 = 4 waves; wave w owns q rows bx*128+w*32..+31.
// Waves issue IN ORDER: R10 placed all 48 MFMAs before the softmax VALU, so MFMA and
// VALU phases alternate and phase-locked blocks leave both pipes half idle (41%/27%).
// Here sched_group_barrier pins an interleave: [S: 2 DS + 3 MFMA]x8, then
// [PV: 2 DS + 3 MFMA + 14 softmax-VALU]x8 -> single-wave dual-issue of PV MFMA under
// softmax VALU. PV always runs (P-frags zero-init on first iter); rescale hoisted to
// loop top (rare branch); k-mask branchless; repack uses 8 shfls (pre-select + xor32).
__global__ __launch_bounds__(256, 2)
void attn_mfma10(const ushort_t* __restrict__ Qh, const ushort_t* __restrict__ Ql,
                 const ushort_t* __restrict__ Khs, const ushort_t* __restrict__ Kls,
                 const ushort_t* __restrict__ Vth, const ushort_t* __restrict__ Vtl,
                 float* __restrict__ Opart, float* __restrict__ mlpart, int tps) {
    __shared__ ushort_t lds[2][4][4096];   // [buf][Kh,Kl,Vh,Vl] 64 KB
    const int head = blockIdx.y;
    const int sp = blockIdx.z;
    const int t = threadIdx.x;
    const int lane = t & 63;
    const int w = t >> 6;
    const int r = lane & 31;
    const int h = lane >> 5;
    const int q0w = blockIdx.x * 128 + w * 32;

    int t_begin = sp * tps;
    int t_end = t_begin + tps; if (t_end > NTILES) t_end = NTILES;

    const size_t kbase = (size_t)head * NPAD * H;
    const int o1 = t * 8, o2 = t * 8 + 2048;

    // Q B-fragments in registers
    int qr = q0w + r; if (qr > N_NODES - 1) qr = N_NODES - 1;
    const size_t qbase = ((size_t)(head * N_NODES + qr)) << 7;
    short8 qfh[8], qfl[8];
#pragma unroll
    for (int s = 0; s < 8; ++s) {
        qfh[s] = *(const short8*)&Qh[qbase + 16 * s + 8 * h];
        qfl[s] = *(const short8*)&Ql[qbase + 16 * s + 8 * h];
    }

    f32x16 O[4];
#pragma unroll
    for (int sub = 0; sub < 4; ++sub)
#pragma unroll
        for (int i = 0; i < 16; ++i) O[sub][i] = 0.f;
    float mrun = -1e30f, lrun = 0.f;
    short8 aPh[2], aPl[2];           // P(it-1) frags; zero on first iter -> PV adds 0
#pragma unroll
    for (int s2 = 0; s2 < 2; ++s2)
#pragma unroll
        for (int j = 0; j < 8; ++j) { aPh[s2][j] = 0; aPl[s2][j] = 0; }
    float alpha_prev = 1.f;
    int resc_prev = 0;

    // prologue: stage K(t_begin) and V(t_begin) (V multiplied by zero P; just finite)
    {
        const ushort_t* sKh = Khs + kbase + (size_t)t_begin * 4096;
        const ushort_t* sKl = Kls + kbase + (size_t)t_begin * 4096;
        const ushort_t* sVh = Vth + (size_t)t_begin * 4096;
        const ushort_t* sVl = Vtl + (size_t)t_begin * 4096;
        gll16(sKh + o1, &lds[0][0][o1]); gll16(sKh + o2, &lds[0][0][o2]);
        gll16(sKl + o1, &lds[0][1][o1]); gll16(sKl + o2, &lds[0][1][o2]);
        gll16(sVh + o1, &lds[0][2][o1]); gll16(sVh + o2, &lds[0][2][o2]);
        gll16(sVl + o1, &lds[0][3][o1]); gll16(sVl + o2, &lds[0][3][o2]);
    }

    for (int it = t_begin; it < t_end; ++it) {
        const int b = (it - t_begin) & 1;
        __syncthreads();   // buf[b] = K(it), V(it-1) staged; prior buf[b^1] reads done

        if (resc_prev) {   // rare after ~6 tiles; applies alpha(it-1) before PV(it-1)
#pragma unroll
            for (int i = 0; i < 16; ++i) {
                int rowq = (i & 3) + 8 * (i >> 2) + 4 * h;
                float a = __shfl(alpha_prev, rowq);
#pragma unroll
                for (int sub = 0; sub < 4; ++sub) O[sub][i] *= a;
            }
        }

        {   // prefetch K(it+1) and V(it) into buf[b^1]
            int nt = it + 1; if (nt >= t_end) nt = t_begin;
            const ushort_t* sKh = Khs + kbase + (size_t)nt * 4096;
            const ushort_t* sKl = Kls + kbase + (size_t)nt * 4096;
            const ushort_t* sVh = Vth + (size_t)it * 4096;
            const ushort_t* sVl = Vtl + (size_t)it * 4096;
            gll16(sKh + o1, &lds[b ^ 1][0][o1]); gll16(sKh + o2, &lds[b ^ 1][0][o2]);
            gll16(sKl + o1, &lds[b ^ 1][1][o1]); gll16(sKl + o2, &lds[b ^ 1][1][o2]);
            gll16(sVh + o1, &lds[b ^ 1][2][o1]); gll16(sVh + o2, &lds[b ^ 1][2][o2]);
            gll16(sVl + o1, &lds[b ^ 1][3][o1]); gll16(sVl + o2, &lds[b ^ 1][3][o2]);
        }
        const ushort_t* lKh = &lds[b][0][0];
        const ushort_t* lKl = &lds[b][1][0];
        const ushort_t* lVh = &lds[b][2][0];   // V(it-1)
        const ushort_t* lVl = &lds[b][3][0];

        // ---- S^T(it) ----
        f32x16 acc;
#pragma unroll
        for (int i = 0; i < 16; ++i) acc[i] = 0.f;
        const int krow = r * H;
#pragma unroll
        for (int s = 0; s < 8; ++s) {
            int cc = ((2 * s + h) ^ (r & 15)) << 3;
            short8 ah = *(const short8*)&lKh[krow + cc];
            short8 al = *(const short8*)&lKl[krow + cc];
            acc = __builtin_amdgcn_mfma_f32_32x32x16_bf16(ah, qfh[s], acc, 0, 0, 0);
            acc = __builtin_amdgcn_mfma_f32_32x32x16_bf16(ah, qfl[s], acc, 0, 0, 0);
            acc = __builtin_amdgcn_mfma_f32_32x32x16_bf16(al, qfh[s], acc, 0, 0, 0);
        }

        // ---- deferred PV(it-1) (independent; woven with softmax below) ----
#pragma unroll
        for (int sub = 0; sub < 4; ++sub) {
            const int vrow = (32 * sub + r) * 32;
#pragma unroll
            for (int s2 = 0; s2 < 2; ++s2) {
                int cc = (((2 * s2 + h) ^ (r & 3)) << 3);
                short8 bh = *(const short8*)&lVh[vrow + cc];
                short8 bl = *(const short8*)&lVl[vrow + cc];
                O[sub] = __builtin_amdgcn_mfma_f32_32x32x16_bf16(aPh[s2], bh, O[sub], 0, 0, 0);
                O[sub] = __builtin_amdgcn_mfma_f32_32x32x16_bf16(aPh[s2], bl, O[sub], 0, 0, 0);
                O[sub] = __builtin_amdgcn_mfma_f32_32x32x16_bf16(aPl[s2], bh, O[sub], 0, 0, 0);
            }
        }

        // ---- online softmax(it), branchless mask ----
        int klim = N_NODES - (it << 5);
        float sv[16];
#pragma unroll
        for (int i = 0; i < 16; ++i) {
            int row = (i & 3) + 8 * (i >> 2) + 4 * h;
            sv[i] = (row < klim) ? acc[i] : -1e30f;
        }
        float tmax = sv[0];
#pragma unroll
        for (int i = 1; i < 16; ++i) tmax = fmaxf(tmax, sv[i]);
        tmax = fmaxf(tmax, __shfl_xor(tmax, 32));
        float mnew = fmaxf(mrun, tmax);
        float alpha = __expf(mrun - mnew);         // ==1 when max unchanged
        resc_prev = (__ballot(mnew > mrun) != 0ull) ? 1 : 0;
        alpha_prev = alpha;
        float p[16];
        float psum = 0.f;
#pragma unroll
        for (int i = 0; i < 16; ++i) { p[i] = __expf(sv[i] - mnew); psum += p[i]; }
        lrun = lrun * alpha + psum;
        mrun = mnew;

        // ---- P(it) repack (8 shfls: pre-select own-half contribution, xor32) ----
        float tmp[8], rv[8];
#pragma unroll
        for (int k = 0; k < 8; ++k) {
            int i0 = (k & 3) + 8 * (k >> 2);
            tmp[k] = h ? p[i0] : p[i0 + 4];
        }
#pragma unroll
        for (int k = 0; k < 8; ++k) rv[k] = __shfl_xor(tmp[k], 32);
#pragma unroll
        for (int s2 = 0; s2 < 2; ++s2) {
#pragma unroll
            for (int j = 0; j < 8; ++j) {
                int c = j & 3;
                float v;
                if (j < 4) v = (h == 0) ? p[c + 8 * s2] : rv[c + 4 * s2];
                else       v = (h == 1) ? p[c + 8 * s2 + 4] : rv[c + 4 * s2];
                unsigned ub = __float_as_uint(v);
                unsigned hb = ub & 0xffff0000u;
                float lo = v - __uint_as_float(hb);
                aPh[s2][j] = (short)(hb >> 16);
                aPl[s2][j] = (short)(__float_as_uint(lo) >> 16);
            }
        }

        // ---- schedule pin: prefetch first, S groups, then PV MFMA woven with VALU ----
        __builtin_amdgcn_sched_group_barrier(0x010, 16, 0);   // 16 VMEM (gll16 prefetch)
#pragma unroll
        for (int g2 = 0; g2 < 8; ++g2) {
            __builtin_amdgcn_sched_group_barrier(0x100, 2, 0);  // 2 DS reads (K)
            __builtin_amdgcn_sched_group_barrier(0x008, 3, 0);  // 3 S-MFMA
        }
#pragma unroll
        for (int g2 = 0; g2 < 8; ++g2) {
            __builtin_amdgcn_sched_group_barrier(0x100, 2, 0);  // 2 DS reads (V)
            __builtin_amdgcn_sched_group_barrier(0x008, 3, 0);  // 3 PV-MFMA
            __builtin_amdgcn_sched_group_barrier(0x002, 14, 0); // 14 softmax/repack VALU
        }
    }

    // ---- epilogue: flush PV(t_end-1) from the last-prefetched buffer ----
    __syncthreads();   // V(t_end-1) staging drained
    {
        const int bl = (t_end - t_begin) & 1;
        const ushort_t* lVh = &lds[bl][2][0];
        const ushort_t* lVl = &lds[bl][3][0];
        if (resc_prev) {
#pragma unroll
            for (int i = 0; i < 16; ++i) {
                int rowq = (i & 3) + 8 * (i >> 2) + 4 * h;
                float a = __shfl(alpha_prev, rowq);
#pragma unroll
                for (int sub = 0; sub < 4; ++sub) O[sub][i] *= a;
            }
        }
#pragma unroll
        for (int sub = 0; sub < 4; ++sub) {
            const int vrow = (32 * sub + r) * 32;
#pragma unroll
            for (int s2 = 0; s2 < 2; ++s2) {
                int cc = (((2 * s2 + h) ^ (r & 3)) << 3);
                short8 bh = *(const short8*)&lVh[vrow + cc];
                short8 bl = *(const short8*)&lVl[vrow + cc];
                O[sub] = __builtin_amdgcn_mfma_f32_32x32x16_bf16(aPh[s2], bh, O[sub], 0, 0, 0);
                O[sub] = __builtin_amdgcn_mfma_f32_32x32x16_bf16(aPh[s2], bl, O[sub], 0, 0, 0);
                O[sub] = __builtin_amdgcn_mfma_f32_32x32x16_bf16(aPl[s2], bh, O[sub], 0, 0, 0);
            }
        }
    }

    lrun += __shfl_xor(lrun, 32);   // deferred cross-half l sum

    // ---- write partials (guard q >= N_NODES) ----
    float* Ob = Opart + (size_t)(sp * NHEADS + head) * NPAD * H;
#pragma unroll
    for (int i = 0; i < 16; ++i) {
        int rowq = (i & 3) + 8 * (i >> 2) + 4 * h;
        int qg = q0w + rowq;
        if (qg < N_NODES) {
            float* dst = &Ob[(size_t)qg * H + r];
#pragma unroll
            for (int sub = 0; sub < 4; ++sub) dst[32 * sub] = O[sub][i];
        }
    }
    if (h == 0 && q0w + r < N_NODES) {
        float2* ml = (float2*)mlpart;
        ml[(size_t)(sp * NHEADS + head) * NPAD + q0w + r] = make_float2(mrun, lrun);
    }
}

// merge split-K partials into hcat (float4)
__global__ __launch_bounds__(256)
void attn_combine(const float* __restrict__ Opart, const float* __restrict__ mlpart,
                  float* __restrict__ hcat, int ns) {
    int idx = blockIdx.x * 256 + threadIdx.x;
    if (idx >= NHEADS * N_NODES * (H / 4)) return;
    int head = idx / (N_NODES * (H / 4));
    int rest = idx - head * N_NODES * (H / 4);
    int q = rest >> 5;
    int d4 = (rest & 31) << 2;
    const float2* ml = (const float2*)mlpart;
    float m = -1e30f;
    for (int s = 0; s < ns; ++s)
        m = fmaxf(m, ml[(size_t)(s * NHEADS + head) * NPAD + q].x);
    float lsum = 0.f;
    float4 o = {0.f, 0.f, 0.f, 0.f};
    for (int s = 0; s < ns; ++s) {
        float2 v = ml[(size_t)(s * NHEADS + head) * NPAD + q];
        float wgt = __expf(v.x - m);
        lsum += v.y * wgt;
        float4 ov = *(const float4*)&Opart[((size_t)(s * NHEADS + head) * NPAD + q) * H + d4];
        o.x += ov.x * wgt; o.y += ov.y * wgt; o.z += ov.z * wgt; o.w += ov.w * wgt;
    }
    float inv = 1.f / lsum;
    float4 res = {o.x * inv, o.y * inv, o.z * inv, o.w * inv};
    *(float4*)&hcat[(size_t)q * HCAT + H + head * H + d4] = res;
}

// ---------------- fused decoder MLP (8 nodes/block) ----------------
__global__ __launch_bounds__(256)
void decoder(const float* __restrict__ hcat,
             const float* __restrict__ Wd0, const float* __restrict__ bd0,
             const float* __restrict__ Wd, const float* __restrict__ bd,
             const float* __restrict__ Wout, const float* __restrict__ bout,
             float* __restrict__ out) {
    __shared__ float s0[8 * HCAT];
    __shared__ float s1[8 * H];
    __shared__ float s2[8 * H];
    int n0 = blockIdx.x * 8;
    int t = threadIdx.x;
    int f = t & (H - 1);
    int g = t >> 7;
    for (int i = t; i < 8 * HCAT; i += 256)
        s0[i] = hcat[(size_t)n0 * HCAT + i];
    __syncthreads();

    float acc[4];
#pragma unroll
    for (int j = 0; j < 4; ++j) acc[j] = bd0[f];
    for (int d = 0; d < HCAT; ++d) {
        float w = Wd0[d * H + f];
#pragma unroll
        for (int j = 0; j < 4; ++j) acc[j] += s0[(g * 4 + j) * HCAT + d] * w;
    }
#pragma unroll
    for (int j = 0; j < 4; ++j) s1[(g * 4 + j) * H + f] = fmaxf(acc[j], 0.f);
    __syncthreads();

#pragma unroll
    for (int j = 0; j < 4; ++j) acc[j] = bd[f];
    for (int d = 0; d < H; ++d) {
        float w = Wd[d * H + f];
#pragma unroll
        for (int j = 0; j < 4; ++j) acc[j] += s1[(g * 4 + j) * H + d] * w;
    }
#pragma unroll
    for (int j = 0; j < 4; ++j) s2[(g * 4 + j) * H + f] = fmaxf(acc[j], 0.f);
    __syncthreads();

#pragma unroll
    for (int j = 0; j < 4; ++j) acc[j] = bd[H + f];
    for (int d = 0; d < H; ++d) {
        float w = Wd[H * H + d * H + f];
#pragma unroll
        for (int j = 0; j < 4; ++j) acc[j] += s2[(g * 4 + j) * H + d] * w;
    }
    __syncthreads();
#pragma unroll
    for (int j = 0; j < 4; ++j) s1[(g * 4 + j) * H + f] = fmaxf(acc[j], 0.f);
    __syncthreads();

    if (t < 24) {
        int n = t / 3, c = t % 3;
        float o = bout[c];
        for (int d = 0; d < H; ++d) o += s1[n * H + d] * Wout[d * 3 + c];
        out[(size_t)(n0 + n) * 3 + c] = o;
    }
}

// ---------------- launch ----------------
extern "C" void kernel_launch(void* const* d_in, const int* in_sizes, int n_in,
                              void* d_out, int out_size, void* d_ws, size_t ws_size,
                              hipStream_t stream) {
    const float* x_rest = (const float*)d_in[0];
    const float* x_rig  = (const float*)d_in[1];
    const int*   e_rest = (const int*)d_in[2];
    const int*   e_rig  = (const int*)d_in[3];
    const float* Wr0 = (const float*)d_in[4];
    const float* br0 = (const float*)d_in[5];
    const float* Wr  = (const float*)d_in[6];
    const float* br  = (const float*)d_in[7];
    const float* Wg0 = (const float*)d_in[8];
    const float* bg0 = (const float*)d_in[9];
    const float* Wg  = (const float*)d_in[10];
    const float* bg  = (const float*)d_in[11];
    const float* Wa  = (const float*)d_in[12];
    const float* ba  = (const float*)d_in[13];
    const float* Wd0 = (const float*)d_in[14];
    const float* bd0 = (const float*)d_in[15];
    const float* Wd  = (const float*)d_in[16];
    const float* bd  = (const float*)d_in[17];
    const float* Wout = (const float*)d_in[18];
    const float* bout = (const float*)d_in[19];
    float* out = (float*)d_out;

    const size_t NH = (size_t)N_NODES * H;
    float* ws = (float*)d_ws;
    float* dinv = ws;                      // 2N
    float* hw   = dinv + 2 * N_NODES;      // 2*NH
    float* hb   = hw + 2 * NH;             // 2*NH
    float* hcat = hb + 2 * NH;             // N*HCAT
    float* ha   = hcat;                    // alias: dead before hcat is written
    float* xg   = hb + NH;                 // alias hb_g: dead before L3 gather writes it
    ushort_t* Qh  = (ushort_t*)(hcat + (size_t)N_NODES * HCAT);
    ushort_t* Ql  = Qh + (size_t)NHEADS * N_NODES * H;
    ushort_t* Khs = Ql + (size_t)NHEADS * N_NODES * H;
    ushort_t* Kls = Khs + (size_t)NHEADS * NPAD * H;
    ushort_t* Vth = Kls + (size_t)NHEADS * NPAD * H;
    ushort_t* Vtl = Vth + (size_t)NTILES * H * 32;
    int* ib   = (int*)(Vtl + (size_t)NTILES * H * 32);
    int* cnt  = ib;                        // 2N
    int* cur  = cnt + 2 * N_NODES;         // 2N
    int* rs   = cur + 2 * N_NODES;         // 2(N+1)
    int* eslot = rs + 2 * (N_NODES + 1);   // 2E
    int* iend  = eslot + 2 * N_EDGES;
    float* Opart = (float*)(((uintptr_t)iend + 15) & ~(uintptr_t)15);

    size_t base_bytes = (size_t)((char*)Opart - (char*)d_ws);
    size_t per_split  = (size_t)NHEADS * NPAD * (H + 2) * sizeof(float);
    int NS = 2;
    if (ws_size >= base_bytes + 5 * per_split + (1u << 20)) NS = 5;
    else if (ws_size >= base_bytes + 4 * per_split + (1u << 20)) NS = 4;
    float* mlpart = Opart + (size_t)NS * NHEADS * NPAD * H;
    int tps = (NTILES + NS - 1) / NS;

    const int gE = (N_EDGES + 255) / 256;

    // ---- CSR build (both graphs per launch) ----
    zero_ints<<<(4 * N_NODES + 255) / 256, 256, 0, stream>>>(cnt, 4 * N_NODES);
    hist2<<<dim3(gE, 2), 256, 0, stream>>>(e_rest, e_rig, cnt);
    scan2<<<2, 1024, 0, stream>>>(cnt, rs, dinv);
    place2<<<dim3(gE, 2), 256, 0, stream>>>(e_rest, e_rig, rs, cur, eslot);

    float* hw_r = hw, * hw_g = hw + NH;
    float* ha_r = ha, * ha_g = ha + NH;
    float* hb_r = hb, * hb_g = hb + NH;

    // L1 (fused): aggregate 3-dim x + GEMM 3->128 + bias + relu, one kernel
    l1_fused<<<dim3(N_NODES / 16, 2), 256, 0, stream>>>(x_rest, x_rig, e_rest, e_rig,
                                                        eslot, rs, dinv, Wr0, Wg0,
                                                        br0, bg0, ha_r, ha_g);
    // L2
    gcn_gemm2<<<dim3(N_NODES / 16, 2), 256, 0, stream>>>(ha_r, ha_g, Wr, Wg, hw_r, hw_g);
    gather2<<<dim3(N_NODES, 2), H, 0, stream>>>(e_rest, e_rig, eslot, rs, hw_r, hw_g, dinv,
                                                br, bg, hb_r, hb_g, H, H);
    // L3: resting -> hcat cols 0:128 (stride 640); rigid -> xg (stride 128)
    gcn_gemm2<<<dim3(N_NODES / 16, 2), 256, 0, stream>>>(hb_r, hb_g, Wr + H * H, Wg + H * H,
                                                         hw_r, hw_g);
    gather2<<<dim3(N_NODES, 2), H, 0, stream>>>(e_rest, e_rig, eslot, rs, hw_r, hw_g, dinv,
                                                br + H, bg + H, hcat, xg, HCAT, H);

    // ---- attention (fused prep: qk + pad + V transpose) ----
    attn_prep<<<1720, 256, 0, stream>>>(hcat, xg, Wa, ba, Qh, Ql, Khs, Kls, Vth, Vtl);
    attn_mfma10<<<dim3(47, NHEADS, NS), 256, 0, stream>>>(Qh, Ql, Khs, Kls, Vth, Vtl,
                                                          Opart, mlpart, tps);
    attn_combine<<<(NHEADS * N_NODES * (H / 4) + 255) / 256, 256, 0, stream>>>(Opart, mlpart,
                                                                               hcat, NS);

    // ---- decoder ----
    decoder<<<N_NODES / 8, 256, 0, stream>>>(hcat, Wd0, bd0, Wd, bd, Wout, bout, out);
}

// Round 14
// 521.498 us; speedup vs baseline: 1.2753x; 1.0925x over previous
//
#include <hip/hip_runtime.h>
#include <math.h>

#define N_NODES 6000
#define N_EDGES 192000
#define H 128
#define NHEADS 4
#define HCAT 640
#define NPAD 6016       // K/partial arrays padded to 6016 rows
#define NTILES 188      // ceil(6000/32)

typedef unsigned short ushort_t;
typedef __attribute__((ext_vector_type(8))) short short8;
typedef __attribute__((ext_vector_type(16))) float f32x16;

__device__ __forceinline__ void bf16split(float x, ushort_t& hi, ushort_t& lo) {
    unsigned ub = __float_as_uint(x);
    unsigned hb = ub & 0xffff0000u;
    float l = x - __uint_as_float(hb);
    hi = (ushort_t)(hb >> 16);
    lo = (ushort_t)(__float_as_uint(l) >> 16);
}

__device__ __forceinline__ void gll16(const ushort_t* g, ushort_t* l) {
    __builtin_amdgcn_global_load_lds((const __attribute__((address_space(1))) void*)g,
                                     (__attribute__((address_space(3))) void*)l, 16, 0, 0);
}

// ---------------- CSR build (both graphs per launch) ----------------
__global__ void zero_ints(int* p, int n) {
    int i = blockIdx.x * 256 + threadIdx.x;
    if (i < n) p[i] = 0;
}

__global__ void hist2(const int* __restrict__ eA, const int* __restrict__ eB,
                      int* __restrict__ cnt) {
    int e = blockIdx.x * 256 + threadIdx.x;
    int z = blockIdx.y;
    const int* edges = z ? eB : eA;
    if (e < N_EDGES) atomicAdd(&cnt[z * N_NODES + edges[N_EDGES + e]], 1);
}

__global__ __launch_bounds__(1024)
void scan2(const int* __restrict__ cnt_all, int* __restrict__ rs_all,
           float* __restrict__ dinv_all) {
    __shared__ int ps[1024];
    int z = blockIdx.x;
    const int* cnt = cnt_all + z * N_NODES;
    int* row_start = rs_all + z * (N_NODES + 1);
    float* dinv = dinv_all + z * N_NODES;
    int t = threadIdx.x;
    int base = t * 6;
    int local[6];
    int s = 0;
#pragma unroll
    for (int j = 0; j < 6; ++j) {
        int idx = base + j;
        int v = (idx < N_NODES) ? cnt[idx] : 0;
        local[j] = s;
        s += v;
        if (idx < N_NODES) dinv[idx] = rsqrtf((float)(v + 1));
    }
    ps[t] = s;
    __syncthreads();
    for (int off = 1; off < 1024; off <<= 1) {
        int v = (t >= off) ? ps[t - off] : 0;
        __syncthreads();
        ps[t] += v;
        __syncthreads();
    }
    int ex = (t > 0) ? ps[t - 1] : 0;
#pragma unroll
    for (int j = 0; j < 6; ++j) {
        int idx = base + j;
        if (idx < N_NODES) row_start[idx] = ex + local[j];
    }
    if (t == 1023) row_start[N_NODES] = ps[1023];
}

__global__ void place2(const int* __restrict__ eA, const int* __restrict__ eB,
                       const int* __restrict__ rs_all, int* __restrict__ cur_all,
                       int* __restrict__ eslot_all) {
    int e = blockIdx.x * 256 + threadIdx.x;
    int z = blockIdx.y;
    const int* edges = z ? eB : eA;
    if (e < N_EDGES) {
        int tg = edges[N_EDGES + e];
        int p = atomicAdd(&cur_all[z * N_NODES + tg], 1);
        eslot_all[(size_t)z * N_EDGES + rs_all[z * (N_NODES + 1) + tg] + p] = e;
    }
}

// ---------------- fused layer-1: aggregate raw 3-dim x + GEMM 3->128 + bias + relu ----------------
__global__ __launch_bounds__(256)
void l1_fused(const float* __restrict__ xA, const float* __restrict__ xB,
              const int* __restrict__ eA, const int* __restrict__ eB,
              const int* __restrict__ eslot_all, const int* __restrict__ rs_all,
              const float* __restrict__ dinv_all,
              const float* __restrict__ WA, const float* __restrict__ WB,
              const float* __restrict__ bA, const float* __restrict__ bB,
              float* __restrict__ outA, float* __restrict__ outB) {
    __shared__ float xs[16][4];
    int z = blockIdx.y;
    const int* edges = z ? eB : eA;
    const int* eslot = eslot_all + (size_t)z * N_EDGES;
    const int* row_start = rs_all + z * (N_NODES + 1);
    const float* x = z ? xB : xA;
    const float* dv = dinv_all + z * N_NODES;
    const float* W = z ? WB : WA;
    const float* bb = z ? bB : bA;
    float* out = z ? outB : outA;
    int n0 = blockIdx.x * 16;
    int t = threadIdx.x;
    int ln = t >> 4, slot = t & 15;
    int n = n0 + ln;
    float di = dv[n];
    float a0 = 0.f, a1 = 0.f, a2 = 0.f;
    int s0 = row_start[n], s1 = row_start[n + 1];
    for (int i = s0 + slot; i < s1; i += 16) {
        int e = eslot[i];
        int s = edges[e];
        float nr = dv[s] * di;
        a0 += x[s * 3 + 0] * nr;
        a1 += x[s * 3 + 1] * nr;
        a2 += x[s * 3 + 2] * nr;
    }
#pragma unroll
    for (int off = 1; off < 16; off <<= 1) {
        a0 += __shfl_xor(a0, off);
        a1 += __shfl_xor(a1, off);
        a2 += __shfl_xor(a2, off);
    }
    if (slot == 0) {
        xs[ln][0] = a0 + x[n * 3 + 0] * di * di;
        xs[ln][1] = a1 + x[n * 3 + 1] * di * di;
        xs[ln][2] = a2 + x[n * 3 + 2] * di * di;
    }
    __syncthreads();
    int f = t & 127, g = t >> 7;
    float bias = bb[f];
    float w0 = W[0 * H + f], w1 = W[1 * H + f], w2 = W[2 * H + f];
#pragma unroll
    for (int j = 0; j < 8; ++j) {
        int node = g * 8 + j;
        float acc = bias + xs[node][0] * w0 + xs[node][1] * w1 + xs[node][2] * w2;
        out[(size_t)(n0 + node) * H + f] = fmaxf(acc, 0.f);
    }
}

// ---------------- GCN pieces (both graphs per launch) ----------------
__global__ __launch_bounds__(256)
void gcn_gemm2(const float* __restrict__ hinA, const float* __restrict__ hinB,
               const float* __restrict__ WA, const float* __restrict__ WB,
               float* __restrict__ hwA, float* __restrict__ hwB) {
    __shared__ float xs[16 * H];
    int z = blockIdx.y;
    const float* hin = z ? hinB : hinA;
    const float* W = z ? WB : WA;
    float* hw = z ? hwB : hwA;
    int n0 = blockIdx.x * 16;
    int t = threadIdx.x;
    int f = t & (H - 1);
    int g = t >> 7;
    for (int i = t; i < 16 * H; i += 256)
        xs[i] = hin[(size_t)n0 * H + i];
    __syncthreads();
    float acc[8];
#pragma unroll
    for (int j = 0; j < 8; ++j) acc[j] = 0.f;
    for (int d = 0; d < H; ++d) {
        float w = W[d * H + f];
#pragma unroll
        for (int j = 0; j < 8; ++j) acc[j] += xs[(g * 8 + j) * H + d] * w;
    }
#pragma unroll
    for (int j = 0; j < 8; ++j) hw[(size_t)(n0 + g * 8 + j) * H + f] = acc[j];
}

__global__ __launch_bounds__(H)
void gather2(const int* __restrict__ eA, const int* __restrict__ eB,
             const int* __restrict__ eslot_all, const int* __restrict__ rs_all,
             const float* __restrict__ hwA, const float* __restrict__ hwB,
             const float* __restrict__ dinv_all,
             const float* __restrict__ bA, const float* __restrict__ bB,
             float* __restrict__ outA, float* __restrict__ outB, int osA, int osB) {
    __shared__ int ssrc[128];
    __shared__ float snrm[128];
    int z = blockIdx.y;
    const int* edges = z ? eB : eA;
    const int* eslot = eslot_all + (size_t)z * N_EDGES;
    const int* row_start = rs_all + z * (N_NODES + 1);
    const float* hw = z ? hwB : hwA;
    const float* dinv = dinv_all + z * N_NODES;
    const float* b = z ? bB : bA;
    float* out = z ? outB : outA;
    int ostride = z ? osB : osA;

    int tg = blockIdx.x, f = threadIdx.x;
    int s0 = row_start[tg], s1 = row_start[tg + 1];
    float di = dinv[tg];
    float acc = hw[(size_t)tg * H + f] * di * di;
    for (int base = s0; base < s1; base += 128) {
        int cnt = min(128, s1 - base);
        __syncthreads();
        if (f < cnt) {
            int e = eslot[base + f];
            int s = edges[e];
            ssrc[f] = s;
            snrm[f] = dinv[s] * di;
        }
        __syncthreads();
        for (int i = 0; i < cnt; ++i)
            acc += hw[(size_t)ssrc[i] * H + f] * snrm[i];
    }
    float v = acc + b[f];
    out[(size_t)tg * ostride + f] = v > 0.f ? v : 0.f;
}

// ---------------- fused attn prep: qk projections + K pad zero + V transpose ----------------
// flat grid 1720 x 256: [0,1500) qk (head=bx/375); [1500,1688) cvt tile; [1688,1720) pad
__global__ __launch_bounds__(256)
void attn_prep(const float* __restrict__ qs, const float* __restrict__ xg,
               const float* __restrict__ Wa, const float* __restrict__ ba,
               ushort_t* __restrict__ Qh, ushort_t* __restrict__ Ql,
               ushort_t* __restrict__ Khs, ushort_t* __restrict__ Kls,
               ushort_t* __restrict__ Vth, ushort_t* __restrict__ Vtl) {
    __shared__ float smem[4224];
    int bx = blockIdx.x;
    int t = threadIdx.x;
    if (bx < 1500) {
        // ---- qk ----
        int head = bx / 375;
        int n0 = (bx - head * 375) * 16;
        float* xs = smem;   // [2][16][128]
        int f = t & (H - 1);
        int g = t >> 7;
        for (int i = t; i < 2 * 16 * H; i += 256) {
            int which = i >> 11;
            int rem = i & 2047;
            int row = rem >> 7, col = rem & 127;
            xs[i] = which ? xg[(size_t)(n0 + row) * H + col]
                          : qs[(size_t)(n0 + row) * HCAT + col];
        }
        __syncthreads();
        const float* W = Wa + (size_t)head * H * H;
        float bias = ba[head * H + f];
        float acc[16];
#pragma unroll
        for (int j = 0; j < 16; ++j) acc[j] = bias;
        for (int d = 0; d < H; ++d) {
            float w = W[d * H + f];
#pragma unroll
            for (int j = 0; j < 16; ++j) acc[j] += xs[g * 2048 + j * H + d] * w;
        }
#pragma unroll
        for (int j = 0; j < 16; ++j) {
            int n = n0 + j;
            ushort_t hi, lo;
            bf16split(acc[j], hi, lo);
            if (g == 0) {
                size_t idx = ((size_t)(head * N_NODES + n) << 7) + f;
                Qh[idx] = hi; Ql[idx] = lo;
            } else {
                int pos = (((f >> 3) ^ (n & 15)) << 3) + (f & 7);
                size_t idx = ((size_t)(head * NPAD + n) << 7) + pos;
                Khs[idx] = hi; Kls[idx] = lo;
            }
        }
    } else if (bx < 1688) {
        // ---- V transpose -> tiled swizzled bf16 hi/lo ----
        int t0 = bx - 1500;
        float (*vs)[129] = (float(*)[129])smem;
        for (int c = t; c < 32 * 32; c += 256) {
            int row = c >> 5, col4 = (c & 31) << 2;
            int n = t0 * 32 + row;
            float4 v = (n < N_NODES) ? *(const float4*)&xg[(size_t)n * H + col4]
                                     : float4{0.f, 0.f, 0.f, 0.f};
            vs[row][col4 + 0] = v.x; vs[row][col4 + 1] = v.y;
            vs[row][col4 + 2] = v.z; vs[row][col4 + 3] = v.w;
        }
        __syncthreads();
        int d = t & 127;
        int ocb = (t >> 7) * 2;
        size_t base = ((size_t)t0 * H + d) * 32;
#pragma unroll
        for (int oo = 0; oo < 2; ++oo) {
            int oc = ocb + oo;
            int cc = oc ^ (d & 3);
            unsigned uh[4], ul[4];
#pragma unroll
            for (int j = 0; j < 4; ++j) {
                ushort_t h0, l0, h1, l1;
                bf16split(vs[cc * 8 + 2 * j][d], h0, l0);
                bf16split(vs[cc * 8 + 2 * j + 1][d], h1, l1);
                uh[j] = (unsigned)h0 | ((unsigned)h1 << 16);
                ul[j] = (unsigned)l0 | ((unsigned)l1 << 16);
            }
            *(uint4*)&Vth[base + oc * 8] = make_uint4(uh[0], uh[1], uh[2], uh[3]);
            *(uint4*)&Vtl[base + oc * 8] = make_uint4(ul[0], ul[1], ul[2], ul[3]);
        }
    } else {
        // ---- zero pad K rows 6000..6015 ----
        int i = (bx - 1688) * 256 + t;
        if (i < NHEADS * 16 * H) {
            int head = i / (16 * H);
            int rest = i - head * 16 * H;
            int n = N_NODES + (rest >> 7);
            int f = rest & 127;
            size_t idx = ((size_t)(head * NPAD + n) << 7) + f;
            Khs[idx] = 0; Kls[idx] = 0;
        }
    }
}

// ---------------- MFMA flash attention: deferred-PV interleave (R10 verbatim) ----------------
// grid (47, NHEADS, NS), block 256 = 4 waves; wave w owns q rows bx*128+w*32..+31.
// Buffer slot for iteration it holds K(it) AND V(it-1); deferred PV(it-1) issues after
// S(it); no schedule pins (R13's sched_group_barrier regressed: conflicts +66%, LDS +16KB).
__global__ __launch_bounds__(256, 2)
void attn_mfma7(const ushort_t* __restrict__ Qh, const ushort_t* __restrict__ Ql,
                const ushort_t* __restrict__ Khs, const ushort_t* __restrict__ Kls,
                const ushort_t* __restrict__ Vth, const ushort_t* __restrict__ Vtl,
                float* __restrict__ Opart, float* __restrict__ mlpart, int tps) {
    __shared__ ushort_t lds[2][4][4096];   // [buf][Kh,Kl,Vh,Vl] 64 KB
    const int head = blockIdx.y;
    const int sp = blockIdx.z;
    const int t = threadIdx.x;
    const int lane = t & 63;
    const int w = t >> 6;
    const int r = lane & 31;
    const int h = lane >> 5;
    const int q0w = blockIdx.x * 128 + w * 32;

    int t_begin = sp * tps;
    int t_end = t_begin + tps; if (t_end > NTILES) t_end = NTILES;

    const size_t kbase = (size_t)head * NPAD * H;
    const int o1 = t * 8, o2 = t * 8 + 2048;

    // Q B-fragments in registers: rows q0w+r (clamped), dims 16s+8h+j
    int qr = q0w + r; if (qr > N_NODES - 1) qr = N_NODES - 1;
    const size_t qbase = ((size_t)(head * N_NODES + qr)) << 7;
    short8 qfh[8], qfl[8];
#pragma unroll
    for (int s = 0; s < 8; ++s) {
        qfh[s] = *(const short8*)&Qh[qbase + 16 * s + 8 * h];
        qfl[s] = *(const short8*)&Ql[qbase + 16 * s + 8 * h];
    }

    f32x16 O[4];
#pragma unroll
    for (int sub = 0; sub < 4; ++sub)
#pragma unroll
        for (int i = 0; i < 16; ++i) O[sub][i] = 0.f;
    float mrun = -1e30f, lrun = 0.f;   // lrun per-half; cross-half sum at end
    short8 aPh[2], aPl[2];             // P(it-1) A-frags, consumed one iter later
    float alpha_prev = 1.f;
    int resc_prev = 0;

    // prologue: stage K(t_begin) into buf 0 (V slot of buf0 unused on first iter)
    {
        const ushort_t* sKh = Khs + kbase + (size_t)t_begin * 4096;
        const ushort_t* sKl = Kls + kbase + (size_t)t_begin * 4096;
        gll16(sKh + o1, &lds[0][0][o1]); gll16(sKh + o2, &lds[0][0][o2]);
        gll16(sKl + o1, &lds[0][1][o1]); gll16(sKl + o2, &lds[0][1][o2]);
    }

    for (int it = t_begin; it < t_end; ++it) {
        const int b = (it - t_begin) & 1;
        __syncthreads();   // buf[b] = K(it), V(it-1) staged; prior buf[b^1] reads done
        {   // prefetch K(it+1) and V(it) into buf[b^1]
            int nt = it + 1; if (nt >= t_end) nt = t_begin;
            const ushort_t* sKh = Khs + kbase + (size_t)nt * 4096;
            const ushort_t* sKl = Kls + kbase + (size_t)nt * 4096;
            const ushort_t* sVh = Vth + (size_t)it * 4096;
            const ushort_t* sVl = Vtl + (size_t)it * 4096;
            gll16(sKh + o1, &lds[b ^ 1][0][o1]); gll16(sKh + o2, &lds[b ^ 1][0][o2]);
            gll16(sKl + o1, &lds[b ^ 1][1][o1]); gll16(sKl + o2, &lds[b ^ 1][1][o2]);
            gll16(sVh + o1, &lds[b ^ 1][2][o1]); gll16(sVh + o2, &lds[b ^ 1][2][o2]);
            gll16(sVl + o1, &lds[b ^ 1][3][o1]); gll16(sVl + o2, &lds[b ^ 1][3][o2]);
        }
        const ushort_t* lKh = &lds[b][0][0];
        const ushort_t* lKl = &lds[b][1][0];
        const ushort_t* lVh = &lds[b][2][0];   // V(it-1)
        const ushort_t* lVl = &lds[b][3][0];

        // ---- S^T(it) = (Kh+Kl)(Qh+Ql)^T, dropping lo*lo ----
        f32x16 acc;
#pragma unroll
        for (int i = 0; i < 16; ++i) acc[i] = 0.f;
        const int krow = r * H;
#pragma unroll
        for (int s = 0; s < 8; ++s) {
            int cc = ((2 * s + h) ^ (r & 15)) << 3;
            short8 ah = *(const short8*)&lKh[krow + cc];
            short8 al = *(const short8*)&lKl[krow + cc];
            acc = __builtin_amdgcn_mfma_f32_32x32x16_bf16(ah, qfh[s], acc, 0, 0, 0);
            acc = __builtin_amdgcn_mfma_f32_32x32x16_bf16(ah, qfl[s], acc, 0, 0, 0);
            acc = __builtin_amdgcn_mfma_f32_32x32x16_bf16(al, qfh[s], acc, 0, 0, 0);
        }

        // ---- deferred PV(it-1): independent of acc -> overlaps S + this softmax ----
        if (it != t_begin) {
            if (resc_prev) {
#pragma unroll
                for (int i = 0; i < 16; ++i) {
                    int rowq = (i & 3) + 8 * (i >> 2) + 4 * h;
                    float a = __shfl(alpha_prev, rowq);
#pragma unroll
                    for (int sub = 0; sub < 4; ++sub) O[sub][i] *= a;
                }
            }
#pragma unroll
            for (int sub = 0; sub < 4; ++sub) {
                const int vrow = (32 * sub + r) * 32;
#pragma unroll
                for (int s2 = 0; s2 < 2; ++s2) {
                    int cc = (((2 * s2 + h) ^ (r & 3)) << 3);
                    short8 bh = *(const short8*)&lVh[vrow + cc];
                    short8 bl = *(const short8*)&lVl[vrow + cc];
                    O[sub] = __builtin_amdgcn_mfma_f32_32x32x16_bf16(aPh[s2], bh, O[sub], 0, 0, 0);
                    O[sub] = __builtin_amdgcn_mfma_f32_32x32x16_bf16(aPh[s2], bl, O[sub], 0, 0, 0);
                    O[sub] = __builtin_amdgcn_mfma_f32_32x32x16_bf16(aPl[s2], bh, O[sub], 0, 0, 0);
                }
            }
        }

        // ---- online softmax(it) ----
        float sv[16];
#pragma unroll
        for (int i = 0; i < 16; ++i) sv[i] = acc[i];
        int klim = N_NODES - (it << 5);
        if (klim < 32) {
#pragma unroll
            for (int i = 0; i < 16; ++i) {
                int row = (i & 3) + 8 * (i >> 2) + 4 * h;
                if (row >= klim) sv[i] = -1e30f;
            }
        }
        float tmax = sv[0];
#pragma unroll
        for (int i = 1; i < 16; ++i) tmax = fmaxf(tmax, sv[i]);
        tmax = fmaxf(tmax, __shfl_xor(tmax, 32));
        float mnew = fmaxf(mrun, tmax);
        float p[16];
        float psum = 0.f;
#pragma unroll
        for (int i = 0; i < 16; ++i) { p[i] = __expf(sv[i] - mnew); psum += p[i]; }

        if (__ballot(mnew > mrun)) {
            float alpha = __expf(mrun - mnew);
            lrun *= alpha;
            alpha_prev = alpha;
            resc_prev = 1;
        } else {
            resc_prev = 0;
        }
        lrun += psum;
        mrun = mnew;

        // ---- P(it) repack: C-layout (transposed) -> A-operand frags for next iter ----
        float pr[16];
#pragma unroll
        for (int i = 0; i < 16; ++i) pr[i] = __shfl_xor(p[i], 32);
#pragma unroll
        for (int s2 = 0; s2 < 2; ++s2) {
#pragma unroll
            for (int j = 0; j < 8; ++j) {
                int c = j & 3;
                float v;
                if (j < 4) v = (h == 0) ? p[c + 8 * s2] : pr[c + 8 * s2 + 4];
                else       v = (h == 1) ? p[c + 8 * s2 + 4] : pr[c + 8 * s2];
                unsigned ub = __float_as_uint(v);
                unsigned hb = ub & 0xffff0000u;
                float lo = v - __uint_as_float(hb);
                aPh[s2][j] = (short)(hb >> 16);
                aPl[s2][j] = (short)(__float_as_uint(lo) >> 16);
            }
        }
    }

    // ---- epilogue: flush PV(t_end-1) from the last-prefetched buffer ----
    __syncthreads();   // V(t_end-1) staging drained
    {
        const int bl = (t_end - t_begin) & 1;
        const ushort_t* lVh = &lds[bl][2][0];
        const ushort_t* lVl = &lds[bl][3][0];
        if (resc_prev) {
#pragma unroll
            for (int i = 0; i < 16; ++i) {
                int rowq = (i & 3) + 8 * (i >> 2) + 4 * h;
                float a = __shfl(alpha_prev, rowq);
#pragma unroll
                for (int sub = 0; sub < 4; ++sub) O[sub][i] *= a;
            }
        }
#pragma unroll
        for (int sub = 0; sub < 4; ++sub) {
            const int vrow = (32 * sub + r) * 32;
#pragma unroll
            for (int s2 = 0; s2 < 2; ++s2) {
                int cc = (((2 * s2 + h) ^ (r & 3)) << 3);
                short8 bh = *(const short8*)&lVh[vrow + cc];
                short8 bl = *(const short8*)&lVl[vrow + cc];
                O[sub] = __builtin_amdgcn_mfma_f32_32x32x16_bf16(aPh[s2], bh, O[sub], 0, 0, 0);
                O[sub] = __builtin_amdgcn_mfma_f32_32x32x16_bf16(aPh[s2], bl, O[sub], 0, 0, 0);
                O[sub] = __builtin_amdgcn_mfma_f32_32x32x16_bf16(aPl[s2], bh, O[sub], 0, 0, 0);
            }
        }
    }

    lrun += __shfl_xor(lrun, 32);   // deferred cross-half l sum

    // ---- write partials (guard q >= N_NODES) ----
    float* Ob = Opart + (size_t)(sp * NHEADS + head) * NPAD * H;
#pragma unroll
    for (int i = 0; i < 16; ++i) {
        int rowq = (i & 3) + 8 * (i >> 2) + 4 * h;
        int qg = q0w + rowq;
        if (qg < N_NODES) {
            float* dst = &Ob[(size_t)qg * H + r];
#pragma unroll
            for (int sub = 0; sub < 4; ++sub) dst[32 * sub] = O[sub][i];
        }
    }
    if (h == 0 && q0w + r < N_NODES) {
        float2* ml = (float2*)mlpart;
        ml[(size_t)(sp * NHEADS + head) * NPAD + q0w + r] = make_float2(mrun, lrun);
    }
}

// merge split-K partials into hcat (float4)
__global__ __launch_bounds__(256)
void attn_combine(const float* __restrict__ Opart, const float* __restrict__ mlpart,
                  float* __restrict__ hcat, int ns) {
    int idx = blockIdx.x * 256 + threadIdx.x;
    if (idx >= NHEADS * N_NODES * (H / 4)) return;
    int head = idx / (N_NODES * (H / 4));
    int rest = idx - head * N_NODES * (H / 4);
    int q = rest >> 5;
    int d4 = (rest & 31) << 2;
    const float2* ml = (const float2*)mlpart;
    float m = -1e30f;
    for (int s = 0; s < ns; ++s)
        m = fmaxf(m, ml[(size_t)(s * NHEADS + head) * NPAD + q].x);
    float lsum = 0.f;
    float4 o = {0.f, 0.f, 0.f, 0.f};
    for (int s = 0; s < ns; ++s) {
        float2 v = ml[(size_t)(s * NHEADS + head) * NPAD + q];
        float wgt = __expf(v.x - m);
        lsum += v.y * wgt;
        float4 ov = *(const float4*)&Opart[((size_t)(s * NHEADS + head) * NPAD + q) * H + d4];
        o.x += ov.x * wgt; o.y += ov.y * wgt; o.z += ov.z * wgt; o.w += ov.w * wgt;
    }
    float inv = 1.f / lsum;
    float4 res = {o.x * inv, o.y * inv, o.z * inv, o.w * inv};
    *(float4*)&hcat[(size_t)q * HCAT + H + head * H + d4] = res;
}

// ---------------- fused decoder MLP (8 nodes/block) ----------------
__global__ __launch_bounds__(256)
void decoder(const float* __restrict__ hcat,
             const float* __restrict__ Wd0, const float* __restrict__ bd0,
             const float* __restrict__ Wd, const float* __restrict__ bd,
             const float* __restrict__ Wout, const float* __restrict__ bout,
             float* __restrict__ out) {
    __shared__ float s0[8 * HCAT];
    __shared__ float s1[8 * H];
    __shared__ float s2[8 * H];
    int n0 = blockIdx.x * 8;
    int t = threadIdx.x;
    int f = t & (H - 1);
    int g = t >> 7;
    for (int i = t; i < 8 * HCAT; i += 256)
        s0[i] = hcat[(size_t)n0 * HCAT + i];
    __syncthreads();

    float acc[4];
#pragma unroll
    for (int j = 0; j < 4; ++j) acc[j] = bd0[f];
    for (int d = 0; d < HCAT; ++d) {
        float w = Wd0[d * H + f];
#pragma unroll
        for (int j = 0; j < 4; ++j) acc[j] += s0[(g * 4 + j) * HCAT + d] * w;
    }
#pragma unroll
    for (int j = 0; j < 4; ++j) s1[(g * 4 + j) * H + f] = fmaxf(acc[j], 0.f);
    __syncthreads();

#pragma unroll
    for (int j = 0; j < 4; ++j) acc[j] = bd[f];
    for (int d = 0; d < H; ++d) {
        float w = Wd[d * H + f];
#pragma unroll
        for (int j = 0; j < 4; ++j) acc[j] += s1[(g * 4 + j) * H + d] * w;
    }
#pragma unroll
    for (int j = 0; j < 4; ++j) s2[(g * 4 + j) * H + f] = fmaxf(acc[j], 0.f);
    __syncthreads();

#pragma unroll
    for (int j = 0; j < 4; ++j) acc[j] = bd[H + f];
    for (int d = 0; d < H; ++d) {
        float w = Wd[H * H + d * H + f];
#pragma unroll
        for (int j = 0; j < 4; ++j) acc[j] += s2[(g * 4 + j) * H + d] * w;
    }
    __syncthreads();
#pragma unroll
    for (int j = 0; j < 4; ++j) s1[(g * 4 + j) * H + f] = fmaxf(acc[j], 0.f);
    __syncthreads();

    if (t < 24) {
        int n = t / 3, c = t % 3;
        float o = bout[c];
        for (int d = 0; d < H; ++d) o += s1[n * H + d] * Wout[d * 3 + c];
        out[(size_t)(n0 + n) * 3 + c] = o;
    }
}

// ---------------- launch ----------------
extern "C" void kernel_launch(void* const* d_in, const int* in_sizes, int n_in,
                              void* d_out, int out_size, void* d_ws, size_t ws_size,
                              hipStream_t stream) {
    const float* x_rest = (const float*)d_in[0];
    const float* x_rig  = (const float*)d_in[1];
    const int*   e_rest = (const int*)d_in[2];
    const int*   e_rig  = (const int*)d_in[3];
    const float* Wr0 = (const float*)d_in[4];
    const float* br0 = (const float*)d_in[5];
    const float* Wr  = (const float*)d_in[6];
    const float* br  = (const float*)d_in[7];
    const float* Wg0 = (const float*)d_in[8];
    const float* bg0 = (const float*)d_in[9];
    const float* Wg  = (const float*)d_in[10];
    const float* bg  = (const float*)d_in[11];
    const float* Wa  = (const float*)d_in[12];
    const float* ba  = (const float*)d_in[13];
    const float* Wd0 = (const float*)d_in[14];
    const float* bd0 = (const float*)d_in[15];
    const float* Wd  = (const float*)d_in[16];
    const float* bd  = (const float*)d_in[17];
    const float* Wout = (const float*)d_in[18];
    const float* bout = (const float*)d_in[19];
    float* out = (float*)d_out;

    const size_t NH = (size_t)N_NODES * H;
    float* ws = (float*)d_ws;
    float* dinv = ws;                      // 2N
    float* hw   = dinv + 2 * N_NODES;      // 2*NH
    float* hb   = hw + 2 * NH;             // 2*NH
    float* hcat = hb + 2 * NH;             // N*HCAT
    float* ha   = hcat;                    // alias: dead before hcat is written
    float* xg   = hb + NH;                 // alias hb_g: dead before L3 gather writes it
    ushort_t* Qh  = (ushort_t*)(hcat + (size_t)N_NODES * HCAT);
    ushort_t* Ql  = Qh + (size_t)NHEADS * N_NODES * H;
    ushort_t* Khs = Ql + (size_t)NHEADS * N_NODES * H;
    ushort_t* Kls = Khs + (size_t)NHEADS * NPAD * H;
    ushort_t* Vth = Kls + (size_t)NHEADS * NPAD * H;
    ushort_t* Vtl = Vth + (size_t)NTILES * H * 32;
    int* ib   = (int*)(Vtl + (size_t)NTILES * H * 32);
    int* cnt  = ib;                        // 2N
    int* cur  = cnt + 2 * N_NODES;         // 2N
    int* rs   = cur + 2 * N_NODES;         // 2(N+1)
    int* eslot = rs + 2 * (N_NODES + 1);   // 2E
    int* iend  = eslot + 2 * N_EDGES;
    float* Opart = (float*)(((uintptr_t)iend + 15) & ~(uintptr_t)15);

    size_t base_bytes = (size_t)((char*)Opart - (char*)d_ws);
    size_t per_split  = (size_t)NHEADS * NPAD * (H + 2) * sizeof(float);
    int NS = 2;
    if (ws_size >= base_bytes + 5 * per_split + (1u << 20)) NS = 5;
    else if (ws_size >= base_bytes + 4 * per_split + (1u << 20)) NS = 4;
    float* mlpart = Opart + (size_t)NS * NHEADS * NPAD * H;
    int tps = (NTILES + NS - 1) / NS;

    const int gE = (N_EDGES + 255) / 256;

    // ---- CSR build (both graphs per launch) ----
    zero_ints<<<(4 * N_NODES + 255) / 256, 256, 0, stream>>>(cnt, 4 * N_NODES);
    hist2<<<dim3(gE, 2), 256, 0, stream>>>(e_rest, e_rig, cnt);
    scan2<<<2, 1024, 0, stream>>>(cnt, rs, dinv);
    place2<<<dim3(gE, 2), 256, 0, stream>>>(e_rest, e_rig, rs, cur, eslot);

    float* hw_r = hw, * hw_g = hw + NH;
    float* ha_r = ha, * ha_g = ha + NH;
    float* hb_r = hb, * hb_g = hb + NH;

    // L1 (fused): aggregate 3-dim x + GEMM 3->128 + bias + relu, one kernel
    l1_fused<<<dim3(N_NODES / 16, 2), 256, 0, stream>>>(x_rest, x_rig, e_rest, e_rig,
                                                        eslot, rs, dinv, Wr0, Wg0,
                                                        br0, bg0, ha_r, ha_g);
    // L2
    gcn_gemm2<<<dim3(N_NODES / 16, 2), 256, 0, stream>>>(ha_r, ha_g, Wr, Wg, hw_r, hw_g);
    gather2<<<dim3(N_NODES, 2), H, 0, stream>>>(e_rest, e_rig, eslot, rs, hw_r, hw_g, dinv,
                                                br, bg, hb_r, hb_g, H, H);
    // L3: resting -> hcat cols 0:128 (stride 640); rigid -> xg (stride 128)
    gcn_gemm2<<<dim3(N_NODES / 16, 2), 256, 0, stream>>>(hb_r, hb_g, Wr + H * H, Wg + H * H,
                                                         hw_r, hw_g);
    gather2<<<dim3(N_NODES, 2), H, 0, stream>>>(e_rest, e_rig, eslot, rs, hw_r, hw_g, dinv,
                                                br + H, bg + H, hcat, xg, HCAT, H);

    // ---- attention (fused prep: qk + pad + V transpose) ----
    attn_prep<<<1720, 256, 0, stream>>>(hcat, xg, Wa, ba, Qh, Ql, Khs, Kls, Vth, Vtl);
    attn_mfma7<<<dim3(47, NHEADS, NS), 256, 0, stream>>>(Qh, Ql, Khs, Kls, Vth, Vtl,
                                                         Opart, mlpart, tps);
    attn_combine<<<(NHEADS * N_NODES * (H / 4) + 255) / 256, 256, 0, stream>>>(Opart, mlpart,
                                                                               hcat, NS);

    // ---- decoder ----
    decoder<<<N_NODES / 8, 256, 0, stream>>>(hcat, Wd0, bd0, Wd, bd, Wout, bout, out);
}